// Round 4
// baseline (1209.619 us; speedup 1.0000x reference)
//
#include <hip/hip_runtime.h>
#include <hip/hip_bf16.h>

#define T_DIM 1024
#define B_DIM 32
#define D_DIM 256
#define TRACE 64
#define CTX 16
#define OUT_DIM 256
#define TB (T_DIM * B_DIM)          // 32768 rows
#define KZ (2 * TRACE * CTX)        // 2048

// ---------------------------------------------------------------------------
// K0a: classify `start` buffer encoding from its byte pattern.
//   bool  (1B): nonzero bytes at i%4==1 somewhere        -> flag 1
//   f32 0/1.0: bytes [00 00 80 3F]: i%4==3 nonzero       -> flag 2
//   int32 0/1: only i%4==0 nonzero; i%8==4 hits odd elems-> flag 0
//   int64 0/1: nonzero only at i%8==0                    -> flag 3
// ---------------------------------------------------------------------------
__global__ void k_start_detect(const unsigned char* __restrict__ s,
                               int* __restrict__ flag) {
  __shared__ int a1, a3, a4;
  if (threadIdx.x == 0) { a1 = 0; a3 = 0; a4 = 0; }
  __syncthreads();
  int l1 = 0, l3 = 0, l4 = 0;
  for (int i = threadIdx.x; i < 32768; i += 256) {
    unsigned char v = s[i];
    if (v) {
      int m4 = i & 3, m8 = i & 7;
      if (m4 == 1) l1 = 1;
      if (m4 == 3) l3 = 1;
      if (m8 == 4) l4 = 1;
    }
  }
  if (l1) atomicOr(&a1, 1);
  if (l3) atomicOr(&a3, 1);
  if (l4) atomicOr(&a4, 1);
  __syncthreads();
  if (threadIdx.x == 0) *flag = a1 ? 1 : (a3 ? 2 : (a4 ? 0 : 3));
}

__global__ void k_start_unpack(const unsigned char* __restrict__ s,
                               const int* __restrict__ flag,
                               int* __restrict__ out) {
  int i = blockIdx.x * 256 + threadIdx.x;   // 32768 total (128 blocks)
  int f = *flag;
  int v;
  if (f == 1)      v = s[i] != 0;
  else if (f == 2) v = reinterpret_cast<const float*>(s)[i] != 0.f;
  else if (f == 3) v = reinterpret_cast<const long long*>(s)[i] != 0;
  else             v = reinterpret_cast<const int*>(s)[i] != 0;
  out[i] = v;
}

// ---------------------------------------------------------------------------
// K1: gated = (x@w_pre + b_pre) * sigmoid(x@w_gate_in + b_gate_in)
// ---------------------------------------------------------------------------
__global__ __launch_bounds__(256) void k_gated(
    const float* __restrict__ x, const float* __restrict__ wg,
    const float* __restrict__ bg, const float* __restrict__ wp,
    const float* __restrict__ bp, float* __restrict__ gated) {
  const int r0 = blockIdx.x * 16;
  const int tid = threadIdx.x;
  __shared__ float xs[16][256];
  for (int c = tid; c < 16 * 64; c += 256) {
    int row = c >> 6, q = c & 63;
    reinterpret_cast<float4*>(&xs[row][0])[q] =
        reinterpret_cast<const float4*>(x + (size_t)(r0 + row) * 256)[q];
  }
  __syncthreads();
  const int o = tid & 63;
  const int rq = tid >> 6;
  float bgo = bg[o], bpo = bp[o];
  float ag[4], ap[4];
#pragma unroll
  for (int j = 0; j < 4; ++j) { ag[j] = bgo; ap[j] = bpo; }
  for (int d = 0; d < 256; ++d) {
    float wgv = wg[d * 64 + o];
    float wpv = wp[d * 64 + o];
#pragma unroll
    for (int j = 0; j < 4; ++j) {
      float xv = xs[rq * 4 + j][d];
      ag[j] = fmaf(xv, wgv, ag[j]);
      ap[j] = fmaf(xv, wpv, ap[j]);
    }
  }
#pragma unroll
  for (int j = 0; j < 4; ++j) {
    float s = 1.f / (1.f + expf(-ag[j]));
    gated[(size_t)(r0 + rq * 4 + j) * 64 + o] = ap[j] * s;
  }
}

// ---------------------------------------------------------------------------
// K2: segmented complex scan over T.
// s_t = start_t ? g_t : s_{t-1} * e^{ab} + g_t
// final_state output: REAL PART ONLY, (B, TRACE, CTX) float32.
// ---------------------------------------------------------------------------
__global__ __launch_bounds__(64) void k_scan(
    const float* __restrict__ gated, const int* __restrict__ start,
    const float* __restrict__ state_re, const float* __restrict__ state_im,
    const float* __restrict__ ffm_a, const float* __restrict__ ffm_b,
    __hip_bfloat16* __restrict__ zin, float* __restrict__ fstate) {
  const int b  = blockIdx.x >> 4;
  const int tg = blockIdx.x & 15;
  const int tid = threadIdx.x;
  const int tl = tid >> 4;
  const int cx = tid & 15;
  const int trace = tg * 4 + tl;
  __shared__ float gs[4096];
  __shared__ int ss[1024];
  for (int i = tid; i < 4096; i += 64) {
    int t = i >> 2, l = i & 3;
    gs[i] = gated[(size_t)t * (B_DIM * TRACE) + b * TRACE + tg * 4 + l];
  }
  for (int i = tid; i < 1024; i += 64) ss[i] = start[i * B_DIM + b];
  __syncthreads();

  float decay = expf(-fabsf(ffm_a[trace]));
  float th = ffm_b[cx];
  float cr = decay * cosf(th);
  float ci = decay * sinf(th);
  float sr = state_re[(b * TRACE + trace) * CTX + cx];
  float si = state_im[(b * TRACE + trace) * CTX + cx];
  const size_t zoff = (size_t)b * KZ + trace * 32 + cx;

  for (int t = 0; t < 1024; ++t) {
    float g = gs[t * 4 + tl];
    int rst = ss[t];
    float nr = fmaf(sr, cr, fmaf(-si, ci, g));
    float ni = fmaf(sr, ci, si * cr);
    sr = rst ? g : nr;
    si = rst ? 0.f : ni;
    __hip_bfloat16* zp = zin + (size_t)t * (B_DIM * KZ) + zoff;
    zp[0]  = __float2bfloat16(sr);
    zp[16] = __float2bfloat16(si);
  }
  // real part only
  fstate[(b * TRACE + trace) * CTX + cx] = sr;
}

// ---------------------------------------------------------------------------
// K3: z = z_in @ w_z + b_z.  M=32768, K=2048, N=256.
// ---------------------------------------------------------------------------
__global__ __launch_bounds__(256) void k_zgemm(
    const __hip_bfloat16* __restrict__ zin, const float* __restrict__ wz,
    const float* __restrict__ bz, float* __restrict__ z) {
  const int r0 = blockIdx.x * 64;
  const int tid = threadIdx.x;
  const int o = tid;
  __shared__ float as[64][64];
  float acc[64];
#pragma unroll
  for (int r = 0; r < 64; ++r) acc[r] = 0.f;

  for (int kt = 0; kt < KZ; kt += 64) {
    for (int c = tid; c < 512; c += 256) {
      int row = c >> 3, q = c & 7;
      uint4 v = *reinterpret_cast<const uint4*>(
          zin + (size_t)(r0 + row) * KZ + kt + q * 8);
      float* dst = &as[row][q * 8];
      dst[0] = __uint_as_float(v.x << 16);
      dst[1] = __uint_as_float(v.x & 0xffff0000u);
      dst[2] = __uint_as_float(v.y << 16);
      dst[3] = __uint_as_float(v.y & 0xffff0000u);
      dst[4] = __uint_as_float(v.z << 16);
      dst[5] = __uint_as_float(v.z & 0xffff0000u);
      dst[6] = __uint_as_float(v.w << 16);
      dst[7] = __uint_as_float(v.w & 0xffff0000u);
    }
    __syncthreads();
    for (int kk = 0; kk < 64; kk += 4) {
      float w0 = wz[(size_t)(kt + kk + 0) * 256 + o];
      float w1 = wz[(size_t)(kt + kk + 1) * 256 + o];
      float w2 = wz[(size_t)(kt + kk + 2) * 256 + o];
      float w3 = wz[(size_t)(kt + kk + 3) * 256 + o];
#pragma unroll
      for (int r = 0; r < 64; ++r) {
        float4 a = *reinterpret_cast<const float4*>(&as[r][kk]);
        acc[r] = fmaf(a.x, w0, acc[r]);
        acc[r] = fmaf(a.y, w1, acc[r]);
        acc[r] = fmaf(a.z, w2, acc[r]);
        acc[r] = fmaf(a.w, w3, acc[r]);
      }
    }
    __syncthreads();
  }
  float bzo = bz[o];
#pragma unroll
  for (int r = 0; r < 64; ++r)
    z[(size_t)(r0 + r) * 256 + o] = acc[r] + bzo;
}

// ---------------------------------------------------------------------------
// K4: gate_out/skip matvecs + LayerNorm(z*go) + skip*(1-go)
// ---------------------------------------------------------------------------
__global__ __launch_bounds__(256) void k_out(
    const float* __restrict__ x, const float* __restrict__ z,
    const float* __restrict__ wgo, const float* __restrict__ bgo,
    const float* __restrict__ wsk, const float* __restrict__ bsk,
    float* __restrict__ out) {
  const int r0 = blockIdx.x * 16;
  const int tid = threadIdx.x;
  const int o = tid;
  __shared__ float xs[16][256];
  __shared__ float red[4][2];
  for (int c = tid; c < 1024; c += 256) {
    int row = c >> 6, q = c & 63;
    reinterpret_cast<float4*>(&xs[row][0])[q] =
        reinterpret_cast<const float4*>(x + (size_t)(r0 + row) * 256)[q];
  }
  __syncthreads();
  float bg = bgo[o], bs = bsk[o];
  float ago[16], ask[16];
#pragma unroll
  for (int r = 0; r < 16; ++r) { ago[r] = bg; ask[r] = bs; }
  for (int d = 0; d < 256; d += 4) {
    float wg0 = wgo[(d + 0) * 256 + o], ws0 = wsk[(d + 0) * 256 + o];
    float wg1 = wgo[(d + 1) * 256 + o], ws1 = wsk[(d + 1) * 256 + o];
    float wg2 = wgo[(d + 2) * 256 + o], ws2 = wsk[(d + 2) * 256 + o];
    float wg3 = wgo[(d + 3) * 256 + o], ws3 = wsk[(d + 3) * 256 + o];
#pragma unroll
    for (int r = 0; r < 16; ++r) {
      float4 xv = *reinterpret_cast<const float4*>(&xs[r][d]);
      ago[r] = fmaf(xv.x, wg0, ago[r]);
      ago[r] = fmaf(xv.y, wg1, ago[r]);
      ago[r] = fmaf(xv.z, wg2, ago[r]);
      ago[r] = fmaf(xv.w, wg3, ago[r]);
      ask[r] = fmaf(xv.x, ws0, ask[r]);
      ask[r] = fmaf(xv.y, ws1, ask[r]);
      ask[r] = fmaf(xv.z, ws2, ask[r]);
      ask[r] = fmaf(xv.w, ws3, ask[r]);
    }
  }
  const int wid = tid >> 6, lane = tid & 63;
  for (int r = 0; r < 16; ++r) {
    float go = 1.f / (1.f + expf(-ago[r]));
    float zv = z[(size_t)(r0 + r) * 256 + o];
    float y = zv * go;
    float s1 = y, s2 = y * y;
#pragma unroll
    for (int off = 32; off > 0; off >>= 1) {
      s1 += __shfl_xor(s1, off);
      s2 += __shfl_xor(s2, off);
    }
    if (lane == 0) { red[wid][0] = s1; red[wid][1] = s2; }
    __syncthreads();
    float t1 = red[0][0] + red[1][0] + red[2][0] + red[3][0];
    float t2 = red[0][1] + red[1][1] + red[2][1] + red[3][1];
    __syncthreads();
    float mu = t1 * (1.f / 256.f);
    float var = t2 * (1.f / 256.f) - mu * mu;
    float rs = rsqrtf(var + 1e-6f);
    float res = (y - mu) * rs + ask[r] * (1.f - go);
    out[(size_t)(r0 + r) * 256 + o] = res;
  }
}

extern "C" void kernel_launch(void* const* d_in, const int* in_sizes, int n_in,
                              void* d_out, int out_size, void* d_ws, size_t ws_size,
                              hipStream_t stream) {
  const float* x         = (const float*)d_in[0];
  const unsigned char* start_raw = (const unsigned char*)d_in[1];
  const float* state_re  = (const float*)d_in[2];
  const float* state_im  = (const float*)d_in[3];
  const float* w_gate_in = (const float*)d_in[4];
  const float* b_gate_in = (const float*)d_in[5];
  const float* w_pre     = (const float*)d_in[6];
  const float* b_pre     = (const float*)d_in[7];
  const float* w_z       = (const float*)d_in[8];
  const float* b_z       = (const float*)d_in[9];
  const float* w_gate_out= (const float*)d_in[10];
  const float* b_gate_out= (const float*)d_in[11];
  const float* w_skip    = (const float*)d_in[12];
  const float* b_skip    = (const float*)d_in[13];
  const float* ffm_a     = (const float*)d_in[14];
  const float* ffm_b     = (const float*)d_in[15];

  // workspace layout
  char* ws = (char*)d_ws;
  int* flag   = (int*)ws;                                   // [0, 4KB)
  int* startw = (int*)(ws + 4096);                          // [4KB, 132KB)
  float* gated = (float*)(ws + ((size_t)1 << 20));          // [1MB, 9MB)
  float* z     = (float*)(ws + ((size_t)9 << 20));          // [9MB, 41MB)
  __hip_bfloat16* zin =
      (__hip_bfloat16*)(ws + ((size_t)41 << 20));           // [41MB, 169MB)

  // output 0: real(final_state) (B,TRACE,CTX) = 32768 floats
  // output 1: out (T,B,256) starting at float offset 32768
  float* fstate = (float*)d_out;
  float* out    = (float*)d_out + B_DIM * TRACE * CTX;

  k_start_detect<<<1, 256, 0, stream>>>(start_raw, flag);
  k_start_unpack<<<TB / 256, 256, 0, stream>>>(start_raw, flag, startw);
  k_gated<<<TB / 16, 256, 0, stream>>>(x, w_gate_in, b_gate_in, w_pre, b_pre, gated);
  k_scan<<<B_DIM * 16, 64, 0, stream>>>(gated, startw, state_re, state_im,
                                        ffm_a, ffm_b, zin, fstate);
  k_zgemm<<<TB / 64, 256, 0, stream>>>(zin, w_z, b_z, z);
  k_out<<<TB / 16, 256, 0, stream>>>(x, z, w_gate_out, b_gate_out,
                                     w_skip, b_skip, out);
}

// Round 6
// 386.126 us; speedup vs baseline: 3.1327x; 3.1327x over previous
//
#include <hip/hip_runtime.h>
#include <hip/hip_bf16.h>

#define T_DIM 1024
#define B_DIM 32
#define D_DIM 256
#define TRACE 64
#define CTX 16
#define OUT_DIM 256
#define TB (T_DIM * B_DIM)          // 32768 rows
#define KZ (2 * TRACE * CTX)        // 2048

typedef short short8 __attribute__((ext_vector_type(8)));
typedef float floatx4 __attribute__((ext_vector_type(4)));

// ---------------------------------------------------------------------------
// K0a: classify `start` buffer encoding from its byte pattern.
// ---------------------------------------------------------------------------
__global__ void k_start_detect(const unsigned char* __restrict__ s,
                               int* __restrict__ flag) {
  __shared__ int a1, a3, a4;
  if (threadIdx.x == 0) { a1 = 0; a3 = 0; a4 = 0; }
  __syncthreads();
  int l1 = 0, l3 = 0, l4 = 0;
  for (int i = threadIdx.x; i < 32768; i += 256) {
    unsigned char v = s[i];
    if (v) {
      int m4 = i & 3, m8 = i & 7;
      if (m4 == 1) l1 = 1;
      if (m4 == 3) l3 = 1;
      if (m8 == 4) l4 = 1;
    }
  }
  if (l1) atomicOr(&a1, 1);
  if (l3) atomicOr(&a3, 1);
  if (l4) atomicOr(&a4, 1);
  __syncthreads();
  if (threadIdx.x == 0) *flag = a1 ? 1 : (a3 ? 2 : (a4 ? 0 : 3));
}

__global__ void k_start_unpack(const unsigned char* __restrict__ s,
                               const int* __restrict__ flag,
                               int* __restrict__ out) {
  int i = blockIdx.x * 256 + threadIdx.x;   // 32768 total (128 blocks)
  int f = *flag;
  int v;
  if (f == 1)      v = s[i] != 0;
  else if (f == 2) v = reinterpret_cast<const float*>(s)[i] != 0.f;
  else if (f == 3) v = reinterpret_cast<const long long*>(s)[i] != 0;
  else             v = reinterpret_cast<const int*>(s)[i] != 0;
  out[i] = v;
}

// ---------------------------------------------------------------------------
// K0b: wzt[n][k] = bf16(w_z[k][n])  (2048x256 f32 -> 256x2048 bf16)
// ---------------------------------------------------------------------------
__global__ __launch_bounds__(256) void k_prep(
    const float* __restrict__ wz, __hip_bfloat16* __restrict__ wzt) {
  const int tk = blockIdx.x & 31;   // k tile 0..31
  const int tn = blockIdx.x >> 5;   // n tile 0..3
  const int k0 = tk * 64, n0 = tn * 64;
  __shared__ float sm[64][65];
  const int tid = threadIdx.x;
  for (int i = tid; i < 4096; i += 256) {
    int r = i >> 6, c = i & 63;
    sm[r][c] = wz[(size_t)(k0 + r) * 256 + n0 + c];
  }
  __syncthreads();
  for (int i = tid; i < 4096; i += 256) {
    int r = i >> 6, c = i & 63;   // r: n-dim, c: k-dim
    wzt[(size_t)(n0 + r) * 2048 + k0 + c] = __float2bfloat16(sm[c][r]);
  }
}

// ---------------------------------------------------------------------------
// K1: gated = (x@w_pre + b_pre) * sigmoid(x@w_gate_in + b_gate_in)
// ---------------------------------------------------------------------------
__global__ __launch_bounds__(256) void k_gated(
    const float* __restrict__ x, const float* __restrict__ wg,
    const float* __restrict__ bg, const float* __restrict__ wp,
    const float* __restrict__ bp, float* __restrict__ gated) {
  const int r0 = blockIdx.x * 16;
  const int tid = threadIdx.x;
  __shared__ float xs[16][256];
  for (int c = tid; c < 16 * 64; c += 256) {
    int row = c >> 6, q = c & 63;
    reinterpret_cast<float4*>(&xs[row][0])[q] =
        reinterpret_cast<const float4*>(x + (size_t)(r0 + row) * 256)[q];
  }
  __syncthreads();
  const int o = tid & 63;
  const int rq = tid >> 6;
  float bgo = bg[o], bpo = bp[o];
  float ag[4], ap[4];
#pragma unroll
  for (int j = 0; j < 4; ++j) { ag[j] = bgo; ap[j] = bpo; }
  for (int d = 0; d < 256; ++d) {
    float wgv = wg[d * 64 + o];
    float wpv = wp[d * 64 + o];
#pragma unroll
    for (int j = 0; j < 4; ++j) {
      float xv = xs[rq * 4 + j][d];
      ag[j] = fmaf(xv, wgv, ag[j]);
      ap[j] = fmaf(xv, wpv, ap[j]);
    }
  }
#pragma unroll
  for (int j = 0; j < 4; ++j) {
    float s = 1.f / (1.f + expf(-ag[j]));
    gated[(size_t)(r0 + rq * 4 + j) * 64 + o] = ap[j] * s;
  }
}

// ---------------------------------------------------------------------------
// K2: segmented complex scan over T. final_state: real part only.
// ---------------------------------------------------------------------------
__global__ __launch_bounds__(64) void k_scan(
    const float* __restrict__ gated, const int* __restrict__ start,
    const float* __restrict__ state_re, const float* __restrict__ state_im,
    const float* __restrict__ ffm_a, const float* __restrict__ ffm_b,
    __hip_bfloat16* __restrict__ zin, float* __restrict__ fstate) {
  const int b  = blockIdx.x >> 4;
  const int tg = blockIdx.x & 15;
  const int tid = threadIdx.x;
  const int tl = tid >> 4;
  const int cx = tid & 15;
  const int trace = tg * 4 + tl;
  __shared__ float gs[4096];
  __shared__ int ss[1024];
  for (int i = tid; i < 4096; i += 64) {
    int t = i >> 2, l = i & 3;
    gs[i] = gated[(size_t)t * (B_DIM * TRACE) + b * TRACE + tg * 4 + l];
  }
  for (int i = tid; i < 1024; i += 64) ss[i] = start[i * B_DIM + b];
  __syncthreads();

  float decay = expf(-fabsf(ffm_a[trace]));
  float th = ffm_b[cx];
  float cr = decay * cosf(th);
  float ci = decay * sinf(th);
  float sr = state_re[(b * TRACE + trace) * CTX + cx];
  float si = state_im[(b * TRACE + trace) * CTX + cx];
  const size_t zoff = (size_t)b * KZ + trace * 32 + cx;

  for (int t = 0; t < 1024; ++t) {
    float g = gs[t * 4 + tl];
    int rst = ss[t];
    float nr = fmaf(sr, cr, fmaf(-si, ci, g));
    float ni = fmaf(sr, ci, si * cr);
    sr = rst ? g : nr;
    si = rst ? 0.f : ni;
    __hip_bfloat16* zp = zin + (size_t)t * (B_DIM * KZ) + zoff;
    zp[0]  = __float2bfloat16(sr);
    zp[16] = __float2bfloat16(si);
  }
  fstate[(b * TRACE + trace) * CTX + cx] = sr;
}

// ---------------------------------------------------------------------------
// K3: z = zin @ wzt^T + bz via bf16 MFMA.  M=32768, K=2048, N=256.
// 128x128 tile, BK=64, 4 waves (2x2), each wave 64x64 = 4x4 16x16x32 frags.
// LDS tiles XOR-swizzled (T2).
// ---------------------------------------------------------------------------
__global__ __launch_bounds__(256) void k_zgemm(
    const __hip_bfloat16* __restrict__ zin, const __hip_bfloat16* __restrict__ wzt,
    const float* __restrict__ bz, float* __restrict__ z) {
  const int r0 = blockIdx.x * 128;   // M tile
  const int n0 = blockIdx.y * 128;   // N tile
  const int tid = threadIdx.x;
  const int l = tid & 63;
  const int wid = tid >> 6;
  const int wr = wid >> 1;           // 0..1
  const int wc = wid & 1;            // 0..1

  __shared__ __align__(16) char ldsA[16384];   // [128][64] bf16 swizzled
  __shared__ __align__(16) char ldsB[16384];   // [128 n][64 k] bf16 swizzled

  floatx4 acc[4][4];
#pragma unroll
  for (int m = 0; m < 4; ++m)
#pragma unroll
    for (int n = 0; n < 4; ++n) acc[m][n] = (floatx4)0.f;

  // precompute swizzled LDS byte offsets for fragment reads
  int aoff[4][2], boff[4][2];
#pragma unroll
  for (int m = 0; m < 4; ++m) {
    int row = wr * 64 + m * 16 + (l & 15);
#pragma unroll
    for (int ks = 0; ks < 2; ++ks) {
      int byte = row * 128 + ks * 64 + (l >> 4) * 16;
      aoff[m][ks] = byte ^ ((row & 7) << 4);
    }
    int col = wc * 64 + m * 16 + (l & 15);
#pragma unroll
    for (int ks = 0; ks < 2; ++ks) {
      int byte = col * 128 + ks * 64 + (l >> 4) * 16;
      boff[m][ks] = byte ^ ((col & 7) << 4);
    }
  }

  for (int kt = 0; kt < KZ; kt += 64) {
    // stage A,B tiles: 1024 chunks of 16B each (128 rows x 8 chunks)
#pragma unroll
    for (int i = 0; i < 4; ++i) {
      int c = tid + i * 256;          // [0,1024)
      int row = c >> 3, kg = c & 7;
      int byte = (row * 128 + kg * 16) ^ ((row & 7) << 4);
      uint4 va = *reinterpret_cast<const uint4*>(
          zin + (size_t)(r0 + row) * KZ + kt + kg * 8);
      *reinterpret_cast<uint4*>(ldsA + byte) = va;
      uint4 vb = *reinterpret_cast<const uint4*>(
          wzt + (size_t)(n0 + row) * KZ + kt + kg * 8);
      *reinterpret_cast<uint4*>(ldsB + byte) = vb;
    }
    __syncthreads();
#pragma unroll
    for (int ks = 0; ks < 2; ++ks) {
      short8 a[4], b[4];
#pragma unroll
      for (int m = 0; m < 4; ++m)
        a[m] = *reinterpret_cast<const short8*>(ldsA + aoff[m][ks]);
#pragma unroll
      for (int n = 0; n < 4; ++n)
        b[n] = *reinterpret_cast<const short8*>(ldsB + boff[n][ks]);
#pragma unroll
      for (int m = 0; m < 4; ++m)
#pragma unroll
        for (int n = 0; n < 4; ++n)
          acc[m][n] = __builtin_amdgcn_mfma_f32_16x16x32_bf16(
              a[m], b[n], acc[m][n], 0, 0, 0);
    }
    __syncthreads();
  }

  // epilogue: D row = 4*(l>>4)+j, col = l&15 within each 16x16 fragment
#pragma unroll
  for (int m = 0; m < 4; ++m) {
#pragma unroll
    for (int n = 0; n < 4; ++n) {
      int gc = n0 + wc * 64 + n * 16 + (l & 15);
      float bzv = bz[gc];
#pragma unroll
      for (int j = 0; j < 4; ++j) {
        int gr = r0 + wr * 64 + m * 16 + (l >> 4) * 4 + j;
        z[(size_t)gr * 256 + gc] = acc[m][n][j] + bzv;
      }
    }
  }
}

// ---------------------------------------------------------------------------
// K4: gate_out/skip matvecs + LayerNorm(z*go) + skip*(1-go)
// ---------------------------------------------------------------------------
__global__ __launch_bounds__(256) void k_out(
    const float* __restrict__ x, const float* __restrict__ z,
    const float* __restrict__ wgo, const float* __restrict__ bgo,
    const float* __restrict__ wsk, const float* __restrict__ bsk,
    float* __restrict__ out) {
  const int r0 = blockIdx.x * 16;
  const int tid = threadIdx.x;
  const int o = tid;
  __shared__ float xs[16][256];
  __shared__ float red[4][2];
  for (int c = tid; c < 1024; c += 256) {
    int row = c >> 6, q = c & 63;
    reinterpret_cast<float4*>(&xs[row][0])[q] =
        reinterpret_cast<const float4*>(x + (size_t)(r0 + row) * 256)[q];
  }
  __syncthreads();
  float bg = bgo[o], bs = bsk[o];
  float ago[16], ask[16];
#pragma unroll
  for (int r = 0; r < 16; ++r) { ago[r] = bg; ask[r] = bs; }
  for (int d = 0; d < 256; d += 4) {
    float wg0 = wgo[(d + 0) * 256 + o], ws0 = wsk[(d + 0) * 256 + o];
    float wg1 = wgo[(d + 1) * 256 + o], ws1 = wsk[(d + 1) * 256 + o];
    float wg2 = wgo[(d + 2) * 256 + o], ws2 = wsk[(d + 2) * 256 + o];
    float wg3 = wgo[(d + 3) * 256 + o], ws3 = wsk[(d + 3) * 256 + o];
#pragma unroll
    for (int r = 0; r < 16; ++r) {
      float4 xv = *reinterpret_cast<const float4*>(&xs[r][d]);
      ago[r] = fmaf(xv.x, wg0, ago[r]);
      ago[r] = fmaf(xv.y, wg1, ago[r]);
      ago[r] = fmaf(xv.z, wg2, ago[r]);
      ago[r] = fmaf(xv.w, wg3, ago[r]);
      ask[r] = fmaf(xv.x, ws0, ask[r]);
      ask[r] = fmaf(xv.y, ws1, ask[r]);
      ask[r] = fmaf(xv.z, ws2, ask[r]);
      ask[r] = fmaf(xv.w, ws3, ask[r]);
    }
  }
  const int wid = tid >> 6, lane = tid & 63;
  for (int r = 0; r < 16; ++r) {
    float go = 1.f / (1.f + expf(-ago[r]));
    float zv = z[(size_t)(r0 + r) * 256 + o];
    float y = zv * go;
    float s1 = y, s2 = y * y;
#pragma unroll
    for (int off = 32; off > 0; off >>= 1) {
      s1 += __shfl_xor(s1, off);
      s2 += __shfl_xor(s2, off);
    }
    if (lane == 0) { red[wid][0] = s1; red[wid][1] = s2; }
    __syncthreads();
    float t1 = red[0][0] + red[1][0] + red[2][0] + red[3][0];
    float t2 = red[0][1] + red[1][1] + red[2][1] + red[3][1];
    __syncthreads();
    float mu = t1 * (1.f / 256.f);
    float var = t2 * (1.f / 256.f) - mu * mu;
    float rs = rsqrtf(var + 1e-6f);
    float res = (y - mu) * rs + ask[r] * (1.f - go);
    out[(size_t)(r0 + r) * 256 + o] = res;
  }
}

extern "C" void kernel_launch(void* const* d_in, const int* in_sizes, int n_in,
                              void* d_out, int out_size, void* d_ws, size_t ws_size,
                              hipStream_t stream) {
  const float* x         = (const float*)d_in[0];
  const unsigned char* start_raw = (const unsigned char*)d_in[1];
  const float* state_re  = (const float*)d_in[2];
  const float* state_im  = (const float*)d_in[3];
  const float* w_gate_in = (const float*)d_in[4];
  const float* b_gate_in = (const float*)d_in[5];
  const float* w_pre     = (const float*)d_in[6];
  const float* b_pre     = (const float*)d_in[7];
  const float* w_z       = (const float*)d_in[8];
  const float* b_z       = (const float*)d_in[9];
  const float* w_gate_out= (const float*)d_in[10];
  const float* b_gate_out= (const float*)d_in[11];
  const float* w_skip    = (const float*)d_in[12];
  const float* b_skip    = (const float*)d_in[13];
  const float* ffm_a     = (const float*)d_in[14];
  const float* ffm_b     = (const float*)d_in[15];

  // workspace layout
  char* ws = (char*)d_ws;
  int* flag   = (int*)ws;                                   // [0, 4KB)
  int* startw = (int*)(ws + 4096);                          // [4KB, 132KB)
  __hip_bfloat16* wzt =
      (__hip_bfloat16*)(ws + ((size_t)1 << 20));            // [1MB, 2MB)
  float* gated = (float*)(ws + ((size_t)2 << 20));          // [2MB, 10MB)
  float* z     = (float*)(ws + ((size_t)10 << 20));         // [10MB, 42MB)
  __hip_bfloat16* zin =
      (__hip_bfloat16*)(ws + ((size_t)42 << 20));           // [42MB, 170MB)

  float* fstate = (float*)d_out;                    // real(final_state), 32768
  float* out    = (float*)d_out + B_DIM * TRACE * CTX;

  k_start_detect<<<1, 256, 0, stream>>>(start_raw, flag);
  k_start_unpack<<<TB / 256, 256, 0, stream>>>(start_raw, flag, startw);
  k_prep<<<128, 256, 0, stream>>>(w_z, wzt);
  k_gated<<<TB / 16, 256, 0, stream>>>(x, w_gate_in, b_gate_in, w_pre, b_pre, gated);
  k_scan<<<B_DIM * 16, 64, 0, stream>>>(gated, startw, state_re, state_im,
                                        ffm_a, ffm_b, zin, fstate);
  k_zgemm<<<dim3(TB / 128, 2), 256, 0, stream>>>(zin, wzt, b_z, z);
  k_out<<<TB / 16, 256, 0, stream>>>(x, z, w_gate_out, b_gate_out,
                                     w_skip, b_skip, out);
}

// Round 7
// 234.413 us; speedup vs baseline: 5.1602x; 1.6472x over previous
//
#include <hip/hip_runtime.h>
#include <hip/hip_bf16.h>

#define T_DIM 1024
#define B_DIM 32
#define D_DIM 256
#define TRACE 64
#define CTX 16
#define OUT_DIM 256
#define TB (T_DIM * B_DIM)          // 32768 rows
#define KZ (2 * TRACE * CTX)        // 2048
#define NP 640                      // concat proj width

typedef short short8 __attribute__((ext_vector_type(8)));
typedef float floatx4 __attribute__((ext_vector_type(4)));

// ---------------------------------------------------------------------------
// K0a: classify `start` buffer encoding from its byte pattern.
// ---------------------------------------------------------------------------
__global__ void k_start_detect(const unsigned char* __restrict__ s,
                               int* __restrict__ flag) {
  __shared__ int a1, a3, a4;
  if (threadIdx.x == 0) { a1 = 0; a3 = 0; a4 = 0; }
  __syncthreads();
  int l1 = 0, l3 = 0, l4 = 0;
  for (int i = threadIdx.x; i < 32768; i += 256) {
    unsigned char v = s[i];
    if (v) {
      int m4 = i & 3, m8 = i & 7;
      if (m4 == 1) l1 = 1;
      if (m4 == 3) l3 = 1;
      if (m8 == 4) l4 = 1;
    }
  }
  if (l1) atomicOr(&a1, 1);
  if (l3) atomicOr(&a3, 1);
  if (l4) atomicOr(&a4, 1);
  __syncthreads();
  if (threadIdx.x == 0) *flag = a1 ? 1 : (a3 ? 2 : (a4 ? 0 : 3));
}

__global__ void k_start_unpack(const unsigned char* __restrict__ s,
                               const int* __restrict__ flag,
                               int* __restrict__ out) {
  int i = blockIdx.x * 256 + threadIdx.x;   // 32768 total (128 blocks)
  int f = *flag;
  int v;
  if (f == 1)      v = s[i] != 0;
  else if (f == 2) v = reinterpret_cast<const float*>(s)[i] != 0.f;
  else if (f == 3) v = reinterpret_cast<const long long*>(s)[i] != 0;
  else             v = reinterpret_cast<const int*>(s)[i] != 0;
  out[i] = v;
}

// ---------------------------------------------------------------------------
// K0b: wzt[n][k] = bf16(w_z[k][n])  (2048x256 f32 -> 256x2048 bf16)
// ---------------------------------------------------------------------------
__global__ __launch_bounds__(256) void k_prep(
    const float* __restrict__ wz, __hip_bfloat16* __restrict__ wzt) {
  const int tk = blockIdx.x & 31;
  const int tn = blockIdx.x >> 5;
  const int k0 = tk * 64, n0 = tn * 64;
  __shared__ float sm[64][65];
  const int tid = threadIdx.x;
  for (int i = tid; i < 4096; i += 256) {
    int r = i >> 6, c = i & 63;
    sm[r][c] = wz[(size_t)(k0 + r) * 256 + n0 + c];
  }
  __syncthreads();
  for (int i = tid; i < 4096; i += 256) {
    int r = i >> 6, c = i & 63;
    wzt[(size_t)(n0 + r) * 2048 + k0 + c] = __float2bfloat16(sm[c][r]);
  }
}

// ---------------------------------------------------------------------------
// K0c: wcat[n][k] = bf16 of transposed concat [w_gate_in|w_pre|w_gate_out|w_skip]
// bcat[n] = concat biases. grid 640 blocks x 256 threads (n=bid, k=tid).
// ---------------------------------------------------------------------------
__global__ __launch_bounds__(256) void k_prep_cat(
    const float* __restrict__ wgi, const float* __restrict__ bgi,
    const float* __restrict__ wpr, const float* __restrict__ bpr,
    const float* __restrict__ wgo, const float* __restrict__ bgo,
    const float* __restrict__ wsk, const float* __restrict__ bsk,
    __hip_bfloat16* __restrict__ wcat, float* __restrict__ bcat) {
  const int n = blockIdx.x, k = threadIdx.x;
  float v, bv;
  if (n < 64)        { v = wgi[k * 64 + n];          bv = bgi[n]; }
  else if (n < 128)  { v = wpr[k * 64 + (n - 64)];   bv = bpr[n - 64]; }
  else if (n < 384)  { v = wgo[k * 256 + (n - 128)]; bv = bgo[n - 128]; }
  else               { v = wsk[k * 256 + (n - 384)]; bv = bsk[n - 384]; }
  wcat[(size_t)n * 256 + k] = __float2bfloat16(v);
  if (k == 0) bcat[n] = bv;
}

// ---------------------------------------------------------------------------
// K0d: xb = bf16(x), 8.4M elements, 8 per thread.
// ---------------------------------------------------------------------------
__global__ __launch_bounds__(256) void k_xbf16(
    const float* __restrict__ x, __hip_bfloat16* __restrict__ xb) {
  size_t i = ((size_t)blockIdx.x * 256 + threadIdx.x) * 8;
  float4 a = *reinterpret_cast<const float4*>(x + i);
  float4 b = *reinterpret_cast<const float4*>(x + i + 4);
  ushort u[8];
  u[0] = __bfloat16_as_ushort(__float2bfloat16(a.x));
  u[1] = __bfloat16_as_ushort(__float2bfloat16(a.y));
  u[2] = __bfloat16_as_ushort(__float2bfloat16(a.z));
  u[3] = __bfloat16_as_ushort(__float2bfloat16(a.w));
  u[4] = __bfloat16_as_ushort(__float2bfloat16(b.x));
  u[5] = __bfloat16_as_ushort(__float2bfloat16(b.y));
  u[6] = __bfloat16_as_ushort(__float2bfloat16(b.z));
  u[7] = __bfloat16_as_ushort(__float2bfloat16(b.w));
  *reinterpret_cast<uint4*>(xb + i) = *reinterpret_cast<uint4*>(u);
}

// ---------------------------------------------------------------------------
// Templated bf16 MFMA GEMM, C = A @ B^T + bias (bf16 out).
// A: MxLDK, B: NxLDK (row-major, i.e. B^T operand), C: Mxldc at col n0.
// 128x128 tile, BK=64, 4 waves (2x2), XOR-swizzled LDS (T2).
// ---------------------------------------------------------------------------
template <int LDK>
__global__ __launch_bounds__(256) void k_gemm_bt(
    const __hip_bfloat16* __restrict__ A, const __hip_bfloat16* __restrict__ Bm,
    const float* __restrict__ bias, __hip_bfloat16* __restrict__ C, int ldc) {
  const int r0 = blockIdx.x * 128;
  const int n0 = blockIdx.y * 128;
  const int tid = threadIdx.x;
  const int l = tid & 63;
  const int wid = tid >> 6;
  const int wr = wid >> 1;
  const int wc = wid & 1;

  __shared__ __align__(16) char ldsA[16384];
  __shared__ __align__(16) char ldsB[16384];

  floatx4 acc[4][4];
#pragma unroll
  for (int m = 0; m < 4; ++m)
#pragma unroll
    for (int n = 0; n < 4; ++n) acc[m][n] = (floatx4)0.f;

  int aoff[4][2], boff[4][2];
#pragma unroll
  for (int m = 0; m < 4; ++m) {
    int row = wr * 64 + m * 16 + (l & 15);
#pragma unroll
    for (int ks = 0; ks < 2; ++ks) {
      int byte = row * 128 + ks * 64 + (l >> 4) * 16;
      aoff[m][ks] = byte ^ ((row & 7) << 4);
    }
    int col = wc * 64 + m * 16 + (l & 15);
#pragma unroll
    for (int ks = 0; ks < 2; ++ks) {
      int byte = col * 128 + ks * 64 + (l >> 4) * 16;
      boff[m][ks] = byte ^ ((col & 7) << 4);
    }
  }

  for (int kt = 0; kt < LDK; kt += 64) {
#pragma unroll
    for (int i = 0; i < 4; ++i) {
      int c = tid + i * 256;          // [0,1024): 128 rows x 8 chunks
      int row = c >> 3, kg = c & 7;
      int byte = (row * 128 + kg * 16) ^ ((row & 7) << 4);
      uint4 va = *reinterpret_cast<const uint4*>(
          A + (size_t)(r0 + row) * LDK + kt + kg * 8);
      *reinterpret_cast<uint4*>(ldsA + byte) = va;
      uint4 vb = *reinterpret_cast<const uint4*>(
          Bm + (size_t)(n0 + row) * LDK + kt + kg * 8);
      *reinterpret_cast<uint4*>(ldsB + byte) = vb;
    }
    __syncthreads();
#pragma unroll
    for (int ks = 0; ks < 2; ++ks) {
      short8 a[4], b[4];
#pragma unroll
      for (int m = 0; m < 4; ++m)
        a[m] = *reinterpret_cast<const short8*>(ldsA + aoff[m][ks]);
#pragma unroll
      for (int n = 0; n < 4; ++n)
        b[n] = *reinterpret_cast<const short8*>(ldsB + boff[n][ks]);
#pragma unroll
      for (int m = 0; m < 4; ++m)
#pragma unroll
        for (int n = 0; n < 4; ++n)
          acc[m][n] = __builtin_amdgcn_mfma_f32_16x16x32_bf16(
              a[m], b[n], acc[m][n], 0, 0, 0);
    }
    __syncthreads();
  }

#pragma unroll
  for (int m = 0; m < 4; ++m) {
#pragma unroll
    for (int n = 0; n < 4; ++n) {
      int gc = n0 + wc * 64 + n * 16 + (l & 15);
      float bzv = bias[gc];
#pragma unroll
      for (int j = 0; j < 4; ++j) {
        int gr = r0 + wr * 64 + m * 16 + (l >> 4) * 4 + j;
        C[(size_t)gr * ldc + gc] = __float2bfloat16(acc[m][n][j] + bzv);
      }
    }
  }
}

// ---------------------------------------------------------------------------
// K2: segmented complex scan over T. gated computed inline from proj.
// final_state: real part only.
// ---------------------------------------------------------------------------
__global__ __launch_bounds__(64) void k_scan(
    const __hip_bfloat16* __restrict__ proj, const int* __restrict__ start,
    const float* __restrict__ state_re, const float* __restrict__ state_im,
    const float* __restrict__ ffm_a, const float* __restrict__ ffm_b,
    __hip_bfloat16* __restrict__ zin, float* __restrict__ fstate) {
  const int b  = blockIdx.x >> 4;
  const int tg = blockIdx.x & 15;
  const int tid = threadIdx.x;
  const int tl = tid >> 4;
  const int cx = tid & 15;
  const int trace = tg * 4 + tl;
  __shared__ float gs[4096];
  __shared__ int ss[1024];
  for (int i = tid; i < 4096; i += 64) {
    int t = i >> 2, l = i & 3;
    size_t base = ((size_t)t * B_DIM + b) * NP + tg * 4 + l;
    float pg = __bfloat162float(proj[base]);        // gate_in preact
    float pp = __bfloat162float(proj[base + 64]);   // pre preact
    gs[i] = pp * (1.f / (1.f + expf(-pg)));
  }
  for (int i = tid; i < 1024; i += 64) ss[i] = start[i * B_DIM + b];
  __syncthreads();

  float decay = expf(-fabsf(ffm_a[trace]));
  float th = ffm_b[cx];
  float cr = decay * cosf(th);
  float ci = decay * sinf(th);
  float sr = state_re[(b * TRACE + trace) * CTX + cx];
  float si = state_im[(b * TRACE + trace) * CTX + cx];
  const size_t zoff = (size_t)b * KZ + trace * 32 + cx;

  for (int t = 0; t < 1024; ++t) {
    float g = gs[t * 4 + tl];
    int rst = ss[t];
    float nr = fmaf(sr, cr, fmaf(-si, ci, g));
    float ni = fmaf(sr, ci, si * cr);
    sr = rst ? g : nr;
    si = rst ? 0.f : ni;
    __hip_bfloat16* zp = zin + (size_t)t * (B_DIM * KZ) + zoff;
    zp[0]  = __float2bfloat16(sr);
    zp[16] = __float2bfloat16(si);
  }
  fstate[(b * TRACE + trace) * CTX + cx] = sr;
}

// ---------------------------------------------------------------------------
// K4: elementwise epilogue: go/skip from proj, LayerNorm(z*go) + skip*(1-go)
// ---------------------------------------------------------------------------
__global__ __launch_bounds__(256) void k_out2(
    const __hip_bfloat16* __restrict__ zb, const __hip_bfloat16* __restrict__ proj,
    float* __restrict__ out) {
  const int r0 = blockIdx.x * 16;
  const int tid = threadIdx.x;
  const int o = tid;
  __shared__ float red[4][2];
  const int wid = tid >> 6, lane = tid & 63;
  for (int r = 0; r < 16; ++r) {
    size_t prow = (size_t)(r0 + r) * NP;
    float pg = __bfloat162float(proj[prow + 128 + o]);
    float ps = __bfloat162float(proj[prow + 384 + o]);
    float zv = __bfloat162float(zb[(size_t)(r0 + r) * 256 + o]);
    float go = 1.f / (1.f + expf(-pg));
    float y = zv * go;
    float s1 = y, s2 = y * y;
#pragma unroll
    for (int off = 32; off > 0; off >>= 1) {
      s1 += __shfl_xor(s1, off);
      s2 += __shfl_xor(s2, off);
    }
    if (lane == 0) { red[wid][0] = s1; red[wid][1] = s2; }
    __syncthreads();
    float t1 = red[0][0] + red[1][0] + red[2][0] + red[3][0];
    float t2 = red[0][1] + red[1][1] + red[2][1] + red[3][1];
    __syncthreads();
    float mu = t1 * (1.f / 256.f);
    float var = t2 * (1.f / 256.f) - mu * mu;
    float rs = rsqrtf(var + 1e-6f);
    out[(size_t)(r0 + r) * 256 + o] = (y - mu) * rs + ps * (1.f - go);
  }
}

extern "C" void kernel_launch(void* const* d_in, const int* in_sizes, int n_in,
                              void* d_out, int out_size, void* d_ws, size_t ws_size,
                              hipStream_t stream) {
  const float* x         = (const float*)d_in[0];
  const unsigned char* start_raw = (const unsigned char*)d_in[1];
  const float* state_re  = (const float*)d_in[2];
  const float* state_im  = (const float*)d_in[3];
  const float* w_gate_in = (const float*)d_in[4];
  const float* b_gate_in = (const float*)d_in[5];
  const float* w_pre     = (const float*)d_in[6];
  const float* b_pre     = (const float*)d_in[7];
  const float* w_z       = (const float*)d_in[8];
  const float* b_z       = (const float*)d_in[9];
  const float* w_gate_out= (const float*)d_in[10];
  const float* b_gate_out= (const float*)d_in[11];
  const float* w_skip    = (const float*)d_in[12];
  const float* b_skip    = (const float*)d_in[13];
  const float* ffm_a     = (const float*)d_in[14];
  const float* ffm_b     = (const float*)d_in[15];

  // workspace layout
  char* ws = (char*)d_ws;
  int* flag   = (int*)ws;                                     // [0, 4KB)
  int* startw = (int*)(ws + 4096);                            // [4KB, 132KB)
  float* bcat = (float*)(ws + (160 << 10));                   // [160KB, 163KB)
  __hip_bfloat16* wcat =
      (__hip_bfloat16*)(ws + (256 << 10));                    // [256KB, 576KB)
  __hip_bfloat16* wzt =
      (__hip_bfloat16*)(ws + ((size_t)1 << 20));              // [1MB, 2MB)
  __hip_bfloat16* xb =
      (__hip_bfloat16*)(ws + ((size_t)2 << 20));              // [2MB, 18MB)
  __hip_bfloat16* zb =
      (__hip_bfloat16*)(ws + ((size_t)18 << 20));             // [18MB, 34MB)
  __hip_bfloat16* proj =
      (__hip_bfloat16*)(ws + ((size_t)34 << 20));             // [34MB, 74MB)
  __hip_bfloat16* zin =
      (__hip_bfloat16*)(ws + ((size_t)74 << 20));             // [74MB, 202MB)

  float* fstate = (float*)d_out;                    // real(final_state), 32768
  float* out    = (float*)d_out + B_DIM * TRACE * CTX;

  k_start_detect<<<1, 256, 0, stream>>>(start_raw, flag);
  k_start_unpack<<<TB / 256, 256, 0, stream>>>(start_raw, flag, startw);
  k_prep<<<128, 256, 0, stream>>>(w_z, wzt);
  k_prep_cat<<<NP, 256, 0, stream>>>(w_gate_in, b_gate_in, w_pre, b_pre,
                                     w_gate_out, b_gate_out, w_skip, b_skip,
                                     wcat, bcat);
  k_xbf16<<<TB * 256 / (256 * 8), 256, 0, stream>>>(x, xb);
  k_gemm_bt<256><<<dim3(TB / 128, NP / 128), 256, 0, stream>>>(
      xb, wcat, bcat, proj, NP);
  k_scan<<<B_DIM * 16, 64, 0, stream>>>(proj, startw, state_re, state_im,
                                        ffm_a, ffm_b, zin, fstate);
  k_gemm_bt<2048><<<dim3(TB / 128, 2), 256, 0, stream>>>(
      zin, wzt, b_z, zb, 256);
  k_out2<<<TB / 16, 256, 0, stream>>>(zb, proj, out);
}

// Round 8
// 228.776 us; speedup vs baseline: 5.2874x; 1.0246x over previous
//
#include <hip/hip_runtime.h>
#include <hip/hip_bf16.h>

#define T_DIM 1024
#define B_DIM 32
#define D_DIM 256
#define TRACE 64
#define CTX 16
#define OUT_DIM 256
#define TB (T_DIM * B_DIM)          // 32768 rows
#define KZ (2 * TRACE * CTX)        // 2048
#define NP 640                      // concat proj width
#define NCH 8                       // scan chunks
#define CHL 128                     // chunk length

typedef short short8 __attribute__((ext_vector_type(8)));
typedef float floatx4 __attribute__((ext_vector_type(4)));
typedef unsigned short ushortx4 __attribute__((ext_vector_type(4)));

__device__ __forceinline__ float bf2f(unsigned short u) {
  return __uint_as_float((unsigned int)u << 16);
}
__device__ __forceinline__ float sigm(float v) {
  return 1.f / (1.f + expf(-v));
}

// ---------------------------------------------------------------------------
// K0a: classify `start` buffer encoding from its byte pattern.
// ---------------------------------------------------------------------------
__global__ void k_start_detect(const unsigned char* __restrict__ s,
                               int* __restrict__ flag) {
  __shared__ int a1, a3, a4;
  if (threadIdx.x == 0) { a1 = 0; a3 = 0; a4 = 0; }
  __syncthreads();
  int l1 = 0, l3 = 0, l4 = 0;
  for (int i = threadIdx.x; i < 32768; i += 256) {
    unsigned char v = s[i];
    if (v) {
      int m4 = i & 3, m8 = i & 7;
      if (m4 == 1) l1 = 1;
      if (m4 == 3) l3 = 1;
      if (m8 == 4) l4 = 1;
    }
  }
  if (l1) atomicOr(&a1, 1);
  if (l3) atomicOr(&a3, 1);
  if (l4) atomicOr(&a4, 1);
  __syncthreads();
  if (threadIdx.x == 0) *flag = a1 ? 1 : (a3 ? 2 : (a4 ? 0 : 3));
}

__global__ void k_start_unpack(const unsigned char* __restrict__ s,
                               const int* __restrict__ flag,
                               int* __restrict__ out) {
  int i = blockIdx.x * 256 + threadIdx.x;   // 32768 total (128 blocks)
  int f = *flag;
  int v;
  if (f == 1)      v = s[i] != 0;
  else if (f == 2) v = reinterpret_cast<const float*>(s)[i] != 0.f;
  else if (f == 3) v = reinterpret_cast<const long long*>(s)[i] != 0;
  else             v = reinterpret_cast<const int*>(s)[i] != 0;
  out[i] = v;
}

// ---------------------------------------------------------------------------
// K0b: wzt[n][k'] = bf16(w_z[perm(k')][n]); zin K is permuted so (re,im) of a
// ctx are adjacent: k' = trace*32 + cx*2 + ri ; source k = trace*32 + ri*16 + cx
// ---------------------------------------------------------------------------
__global__ __launch_bounds__(256) void k_prep(
    const float* __restrict__ wz, __hip_bfloat16* __restrict__ wzt) {
  const int tk = blockIdx.x & 31;
  const int tn = blockIdx.x >> 5;
  const int k0 = tk * 64, n0 = tn * 64;
  __shared__ float sm[64][65];
  const int tid = threadIdx.x;
  for (int i = tid; i < 4096; i += 256) {
    int r = i >> 6, c = i & 63;
    sm[r][c] = wz[(size_t)(k0 + r) * 256 + n0 + c];
  }
  __syncthreads();
  for (int i = tid; i < 4096; i += 256) {
    int r = i >> 6, c = i & 63;   // r: n-within, c: k'-within (output)
    int src = (c & 0x20) | ((c & 1) << 4) | ((c >> 1) & 15);
    wzt[(size_t)(n0 + r) * 2048 + k0 + c] = __float2bfloat16(sm[src][r]);
  }
}

// ---------------------------------------------------------------------------
// K0c: wcat[n][k] = bf16 of transposed concat [w_gate_in|w_pre|w_gate_out|w_skip]
// ---------------------------------------------------------------------------
__global__ __launch_bounds__(256) void k_prep_cat(
    const float* __restrict__ wgi, const float* __restrict__ bgi,
    const float* __restrict__ wpr, const float* __restrict__ bpr,
    const float* __restrict__ wgo, const float* __restrict__ bgo,
    const float* __restrict__ wsk, const float* __restrict__ bsk,
    __hip_bfloat16* __restrict__ wcat, float* __restrict__ bcat) {
  const int n = blockIdx.x, k = threadIdx.x;
  float v, bv;
  if (n < 64)        { v = wgi[k * 64 + n];          bv = bgi[n]; }
  else if (n < 128)  { v = wpr[k * 64 + (n - 64)];   bv = bpr[n - 64]; }
  else if (n < 384)  { v = wgo[k * 256 + (n - 128)]; bv = bgo[n - 128]; }
  else               { v = wsk[k * 256 + (n - 384)]; bv = bsk[n - 384]; }
  wcat[(size_t)n * 256 + k] = __float2bfloat16(v);
  if (k == 0) bcat[n] = bv;
}

// ---------------------------------------------------------------------------
// Proj GEMM: proj = bf16( f32(x) @ wcat^T + bcat ). A is f32 (converted in
// staging). M=32768, K=256, N=640. grid (N/128, M/128); r0=y, n0=x.
// ---------------------------------------------------------------------------
__global__ __launch_bounds__(256) void k_gemm_xproj(
    const float* __restrict__ A, const __hip_bfloat16* __restrict__ Bm,
    const float* __restrict__ bias, __hip_bfloat16* __restrict__ C) {
  const int r0 = blockIdx.y * 128;
  const int n0 = blockIdx.x * 128;
  const int tid = threadIdx.x;
  const int l = tid & 63;
  const int wid = tid >> 6;
  const int wr = wid >> 1;
  const int wc = wid & 1;

  __shared__ __align__(16) char ldsA[16384];
  __shared__ __align__(16) char ldsB[16384];

  floatx4 acc[4][4];
#pragma unroll
  for (int m = 0; m < 4; ++m)
#pragma unroll
    for (int n = 0; n < 4; ++n) acc[m][n] = (floatx4)0.f;

  int aoff[4][2], boff[4][2];
#pragma unroll
  for (int m = 0; m < 4; ++m) {
    int row = wr * 64 + m * 16 + (l & 15);
#pragma unroll
    for (int ks = 0; ks < 2; ++ks) {
      int byte = row * 128 + ks * 64 + (l >> 4) * 16;
      aoff[m][ks] = byte ^ ((row & 7) << 4);
    }
    int col = wc * 64 + m * 16 + (l & 15);
#pragma unroll
    for (int ks = 0; ks < 2; ++ks) {
      int byte = col * 128 + ks * 64 + (l >> 4) * 16;
      boff[m][ks] = byte ^ ((col & 7) << 4);
    }
  }

  for (int kt = 0; kt < 256; kt += 64) {
#pragma unroll
    for (int i = 0; i < 4; ++i) {
      int c = tid + i * 256;          // [0,1024): 128 rows x 8 chunks
      int row = c >> 3, kg = c & 7;
      int byte = (row * 128 + kg * 16) ^ ((row & 7) << 4);
      const float* ap = A + (size_t)(r0 + row) * 256 + kt + kg * 8;
      float4 a0 = *reinterpret_cast<const float4*>(ap);
      float4 a1 = *reinterpret_cast<const float4*>(ap + 4);
      unsigned short u[8];
      u[0] = __bfloat16_as_ushort(__float2bfloat16(a0.x));
      u[1] = __bfloat16_as_ushort(__float2bfloat16(a0.y));
      u[2] = __bfloat16_as_ushort(__float2bfloat16(a0.z));
      u[3] = __bfloat16_as_ushort(__float2bfloat16(a0.w));
      u[4] = __bfloat16_as_ushort(__float2bfloat16(a1.x));
      u[5] = __bfloat16_as_ushort(__float2bfloat16(a1.y));
      u[6] = __bfloat16_as_ushort(__float2bfloat16(a1.z));
      u[7] = __bfloat16_as_ushort(__float2bfloat16(a1.w));
      *reinterpret_cast<uint4*>(ldsA + byte) = *reinterpret_cast<uint4*>(u);
      uint4 vb = *reinterpret_cast<const uint4*>(
          Bm + (size_t)(n0 + row) * 256 + kt + kg * 8);
      *reinterpret_cast<uint4*>(ldsB + byte) = vb;
    }
    __syncthreads();
#pragma unroll
    for (int ks = 0; ks < 2; ++ks) {
      short8 a[4], b[4];
#pragma unroll
      for (int m = 0; m < 4; ++m)
        a[m] = *reinterpret_cast<const short8*>(ldsA + aoff[m][ks]);
#pragma unroll
      for (int n = 0; n < 4; ++n)
        b[n] = *reinterpret_cast<const short8*>(ldsB + boff[n][ks]);
#pragma unroll
      for (int m = 0; m < 4; ++m)
#pragma unroll
        for (int n = 0; n < 4; ++n)
          acc[m][n] = __builtin_amdgcn_mfma_f32_16x16x32_bf16(
              a[m], b[n], acc[m][n], 0, 0, 0);
    }
    __syncthreads();
  }

#pragma unroll
  for (int m = 0; m < 4; ++m) {
#pragma unroll
    for (int n = 0; n < 4; ++n) {
      int gc = n0 + wc * 64 + n * 16 + (l & 15);
      float bzv = bias[gc];
#pragma unroll
      for (int j = 0; j < 4; ++j) {
        int gr = r0 + wr * 64 + m * 16 + (l >> 4) * 4 + j;
        C[(size_t)gr * NP + gc] = __float2bfloat16(acc[m][n][j] + bzv);
      }
    }
  }
}

// ---------------------------------------------------------------------------
// bf16 MFMA GEMM, C = A @ B^T + bias (bf16 out). grid (N/128, M/128).
// ---------------------------------------------------------------------------
template <int LDK>
__global__ __launch_bounds__(256) void k_gemm_bt(
    const __hip_bfloat16* __restrict__ A, const __hip_bfloat16* __restrict__ Bm,
    const float* __restrict__ bias, __hip_bfloat16* __restrict__ C, int ldc) {
  const int r0 = blockIdx.y * 128;
  const int n0 = blockIdx.x * 128;
  const int tid = threadIdx.x;
  const int l = tid & 63;
  const int wid = tid >> 6;
  const int wr = wid >> 1;
  const int wc = wid & 1;

  __shared__ __align__(16) char ldsA[16384];
  __shared__ __align__(16) char ldsB[16384];

  floatx4 acc[4][4];
#pragma unroll
  for (int m = 0; m < 4; ++m)
#pragma unroll
    for (int n = 0; n < 4; ++n) acc[m][n] = (floatx4)0.f;

  int aoff[4][2], boff[4][2];
#pragma unroll
  for (int m = 0; m < 4; ++m) {
    int row = wr * 64 + m * 16 + (l & 15);
#pragma unroll
    for (int ks = 0; ks < 2; ++ks) {
      int byte = row * 128 + ks * 64 + (l >> 4) * 16;
      aoff[m][ks] = byte ^ ((row & 7) << 4);
    }
    int col = wc * 64 + m * 16 + (l & 15);
#pragma unroll
    for (int ks = 0; ks < 2; ++ks) {
      int byte = col * 128 + ks * 64 + (l >> 4) * 16;
      boff[m][ks] = byte ^ ((col & 7) << 4);
    }
  }

  for (int kt = 0; kt < LDK; kt += 64) {
#pragma unroll
    for (int i = 0; i < 4; ++i) {
      int c = tid + i * 256;
      int row = c >> 3, kg = c & 7;
      int byte = (row * 128 + kg * 16) ^ ((row & 7) << 4);
      uint4 va = *reinterpret_cast<const uint4*>(
          A + (size_t)(r0 + row) * LDK + kt + kg * 8);
      *reinterpret_cast<uint4*>(ldsA + byte) = va;
      uint4 vb = *reinterpret_cast<const uint4*>(
          Bm + (size_t)(n0 + row) * LDK + kt + kg * 8);
      *reinterpret_cast<uint4*>(ldsB + byte) = vb;
    }
    __syncthreads();
#pragma unroll
    for (int ks = 0; ks < 2; ++ks) {
      short8 a[4], b[4];
#pragma unroll
      for (int m = 0; m < 4; ++m)
        a[m] = *reinterpret_cast<const short8*>(ldsA + aoff[m][ks]);
#pragma unroll
      for (int n = 0; n < 4; ++n)
        b[n] = *reinterpret_cast<const short8*>(ldsB + boff[n][ks]);
#pragma unroll
      for (int m = 0; m < 4; ++m)
#pragma unroll
        for (int n = 0; n < 4; ++n)
          acc[m][n] = __builtin_amdgcn_mfma_f32_16x16x32_bf16(
              a[m], b[n], acc[m][n], 0, 0, 0);
    }
    __syncthreads();
  }

#pragma unroll
  for (int m = 0; m < 4; ++m) {
#pragma unroll
    for (int n = 0; n < 4; ++n) {
      int gc = n0 + wc * 64 + n * 16 + (l & 15);
      float bzv = bias[gc];
#pragma unroll
      for (int j = 0; j < 4; ++j) {
        int gr = r0 + wr * 64 + m * 16 + (l >> 4) * 4 + j;
        C[(size_t)gr * ldc + gc] = __float2bfloat16(acc[m][n][j] + bzv);
      }
    }
  }
}

// ---------------------------------------------------------------------------
// K2a: per-chunk local scan -> carry s_c (complex) per chain; rst_any per
// (chunk,b). block = (chunk<7, b, tg); 64 threads = (tl 0..3, cx 0..15).
// ---------------------------------------------------------------------------
__global__ __launch_bounds__(64) void k_scan_a(
    const __hip_bfloat16* __restrict__ proj, const int* __restrict__ startw,
    const float* __restrict__ ffm_a, const float* __restrict__ ffm_b,
    float2* __restrict__ carry, int* __restrict__ rstflag) {
  const int c  = blockIdx.x >> 9;        // 0..6
  const int bb = (blockIdx.x >> 4) & 31;
  const int tg = blockIdx.x & 15;
  const int tid = threadIdx.x;
  const int tl = tid >> 4, cx = tid & 15;
  const int trace = tg * 4 + tl;
  const int t0 = c * CHL;
  __shared__ float gs[CHL * 4];
  __shared__ int ss[CHL];
  for (int t = tid; t < CHL; t += 64) {
    size_t base = ((size_t)(t0 + t) * B_DIM + bb) * NP + tg * 4;
    ushortx4 pg4 = *reinterpret_cast<const ushortx4*>(proj + base);
    ushortx4 pp4 = *reinterpret_cast<const ushortx4*>(proj + base + 64);
    float4 o;
    o.x = bf2f(pp4[0]) * sigm(bf2f(pg4[0]));
    o.y = bf2f(pp4[1]) * sigm(bf2f(pg4[1]));
    o.z = bf2f(pp4[2]) * sigm(bf2f(pg4[2]));
    o.w = bf2f(pp4[3]) * sigm(bf2f(pg4[3]));
    *reinterpret_cast<float4*>(&gs[t * 4]) = o;
    ss[t] = startw[(t0 + t) * B_DIM + bb];
  }
  __syncthreads();

  // rst_any for this (chunk,b)
  int lrst = ss[tid] | ss[tid + 64];
  int any = __any(lrst != 0);
  if (tid == 0 && tg == 0) rstflag[c * B_DIM + bb] = any;

  float decay = expf(-fabsf(ffm_a[trace]));
  float th = ffm_b[cx];
  float cr = decay * cosf(th);
  float ci = decay * sinf(th);
  float sr = 0.f, si = 0.f;
  for (int t = 0; t < CHL; ++t) {
    float g = gs[t * 4 + tl];
    int rst = ss[t];
    float nr = fmaf(sr, cr, fmaf(-si, ci, g));
    float ni = fmaf(sr, ci, si * cr);
    sr = rst ? g : nr;
    si = rst ? 0.f : ni;
  }
  carry[((size_t)(c * B_DIM + bb) * TRACE + trace) * CTX + cx] =
      make_float2(sr, si);
}

// ---------------------------------------------------------------------------
// K2c: combine carries -> chunk-start state, then scan chunk writing zin
// (packed re|im<<16 uint per (trace,cx)). chunk 7 writes fstate (real).
// ---------------------------------------------------------------------------
__global__ __launch_bounds__(64) void k_scan_c(
    const __hip_bfloat16* __restrict__ proj, const int* __restrict__ startw,
    const float* __restrict__ state_re, const float* __restrict__ state_im,
    const float* __restrict__ ffm_a, const float* __restrict__ ffm_b,
    const float2* __restrict__ carry, const int* __restrict__ rstflag,
    __hip_bfloat16* __restrict__ zin, float* __restrict__ fstate) {
  const int c  = blockIdx.x >> 9;        // 0..7
  const int bb = (blockIdx.x >> 4) & 31;
  const int tg = blockIdx.x & 15;
  const int tid = threadIdx.x;
  const int tl = tid >> 4, cx = tid & 15;
  const int trace = tg * 4 + tl;
  const int t0 = c * CHL;
  __shared__ float gs[CHL * 4];
  __shared__ int ss[CHL];
  for (int t = tid; t < CHL; t += 64) {
    size_t base = ((size_t)(t0 + t) * B_DIM + bb) * NP + tg * 4;
    ushortx4 pg4 = *reinterpret_cast<const ushortx4*>(proj + base);
    ushortx4 pp4 = *reinterpret_cast<const ushortx4*>(proj + base + 64);
    float4 o;
    o.x = bf2f(pp4[0]) * sigm(bf2f(pg4[0]));
    o.y = bf2f(pp4[1]) * sigm(bf2f(pg4[1]));
    o.z = bf2f(pp4[2]) * sigm(bf2f(pg4[2]));
    o.w = bf2f(pp4[3]) * sigm(bf2f(pg4[3]));
    *reinterpret_cast<float4*>(&gs[t * 4]) = o;
    ss[t] = startw[(t0 + t) * B_DIM + bb];
  }
  __syncthreads();

  float decay = expf(-fabsf(ffm_a[trace]));
  float th = ffm_b[cx];
  float cr = decay * cosf(th);
  float ci = decay * sinf(th);

  // e^{ab*128} by 7 complex squarings
  float pr = cr, pi = ci;
#pragma unroll
  for (int q = 0; q < 7; ++q) {
    float nr = pr * pr - pi * pi;
    float ni = 2.f * pr * pi;
    pr = nr; pi = ni;
  }

  const int chain = (bb * TRACE + trace) * CTX + cx;
  float sr = state_re[chain];
  float si = state_im[chain];
  for (int j = 0; j < c; ++j) {
    float2 cj = carry[((size_t)(j * B_DIM + bb) * TRACE + trace) * CTX + cx];
    if (rstflag[j * B_DIM + bb]) {
      sr = cj.x; si = cj.y;
    } else {
      float nsr = fmaf(pr, sr, fmaf(-pi, si, cj.x));
      float nsi = fmaf(pr, si, fmaf(pi, sr, cj.y));
      sr = nsr; si = nsi;
    }
  }

  const size_t zbase = (size_t)trace * 32 + cx * 2;
  for (int t = 0; t < CHL; ++t) {
    float g = gs[t * 4 + tl];
    int rst = ss[t];
    float nr = fmaf(sr, cr, fmaf(-si, ci, g));
    float ni = fmaf(sr, ci, si * cr);
    sr = rst ? g : nr;
    si = rst ? 0.f : ni;
    unsigned int u = (unsigned int)__bfloat16_as_ushort(__float2bfloat16(sr)) |
                     ((unsigned int)__bfloat16_as_ushort(__float2bfloat16(si)) << 16);
    *reinterpret_cast<unsigned int*>(
        zin + ((size_t)(t0 + t) * B_DIM + bb) * KZ + zbase) = u;
  }
  if (c == NCH - 1) fstate[chain] = sr;
}

// ---------------------------------------------------------------------------
// K4: elementwise epilogue: go/skip from proj, LayerNorm(z*go) + skip*(1-go)
// ---------------------------------------------------------------------------
__global__ __launch_bounds__(256) void k_out2(
    const __hip_bfloat16* __restrict__ zb, const __hip_bfloat16* __restrict__ proj,
    float* __restrict__ out) {
  const int r0 = blockIdx.x * 16;
  const int tid = threadIdx.x;
  const int o = tid;
  __shared__ float red[4][2];
  const int wid = tid >> 6, lane = tid & 63;
  for (int r = 0; r < 16; ++r) {
    size_t prow = (size_t)(r0 + r) * NP;
    float pg = __bfloat162float(proj[prow + 128 + o]);
    float ps = __bfloat162float(proj[prow + 384 + o]);
    float zv = __bfloat162float(zb[(size_t)(r0 + r) * 256 + o]);
    float go = 1.f / (1.f + expf(-pg));
    float y = zv * go;
    float s1 = y, s2 = y * y;
#pragma unroll
    for (int off = 32; off > 0; off >>= 1) {
      s1 += __shfl_xor(s1, off);
      s2 += __shfl_xor(s2, off);
    }
    if (lane == 0) { red[wid][0] = s1; red[wid][1] = s2; }
    __syncthreads();
    float t1 = red[0][0] + red[1][0] + red[2][0] + red[3][0];
    float t2 = red[0][1] + red[1][1] + red[2][1] + red[3][1];
    __syncthreads();
    float mu = t1 * (1.f / 256.f);
    float var = t2 * (1.f / 256.f) - mu * mu;
    float rs = rsqrtf(var + 1e-6f);
    out[(size_t)(r0 + r) * 256 + o] = (y - mu) * rs + ps * (1.f - go);
  }
}

extern "C" void kernel_launch(void* const* d_in, const int* in_sizes, int n_in,
                              void* d_out, int out_size, void* d_ws, size_t ws_size,
                              hipStream_t stream) {
  const float* x         = (const float*)d_in[0];
  const unsigned char* start_raw = (const unsigned char*)d_in[1];
  const float* state_re  = (const float*)d_in[2];
  const float* state_im  = (const float*)d_in[3];
  const float* w_gate_in = (const float*)d_in[4];
  const float* b_gate_in = (const float*)d_in[5];
  const float* w_pre     = (const float*)d_in[6];
  const float* b_pre     = (const float*)d_in[7];
  const float* w_z       = (const float*)d_in[8];
  const float* b_z       = (const float*)d_in[9];
  const float* w_gate_out= (const float*)d_in[10];
  const float* b_gate_out= (const float*)d_in[11];
  const float* w_skip    = (const float*)d_in[12];
  const float* b_skip    = (const float*)d_in[13];
  const float* ffm_a     = (const float*)d_in[14];
  const float* ffm_b     = (const float*)d_in[15];

  // workspace layout
  char* ws = (char*)d_ws;
  int* flag     = (int*)ws;                                   // [0, 4KB)
  int* startw   = (int*)(ws + 4096);                          // [4KB, 132KB)
  int* rstflag  = (int*)(ws + (132 << 10));                   // [132KB, 133KB)
  float* bcat   = (float*)(ws + (160 << 10));                 // [160KB, 163KB)
  __hip_bfloat16* wcat =
      (__hip_bfloat16*)(ws + (256 << 10));                    // [256KB, 576KB)
  __hip_bfloat16* wzt =
      (__hip_bfloat16*)(ws + ((size_t)1 << 20));              // [1MB, 2MB)
  float2* carry = (float2*)(ws + ((size_t)2 << 20));          // [2MB, 4MB)
  __hip_bfloat16* proj =
      (__hip_bfloat16*)(ws + ((size_t)4 << 20));              // [4MB, 44MB)
  __hip_bfloat16* zb =
      (__hip_bfloat16*)(ws + ((size_t)44 << 20));             // [44MB, 60MB)
  __hip_bfloat16* zin =
      (__hip_bfloat16*)(ws + ((size_t)60 << 20));             // [60MB, 188MB)

  float* fstate = (float*)d_out;                    // real(final_state), 32768
  float* out    = (float*)d_out + B_DIM * TRACE * CTX;

  k_start_detect<<<1, 256, 0, stream>>>(start_raw, flag);
  k_start_unpack<<<TB / 256, 256, 0, stream>>>(start_raw, flag, startw);
  k_prep_cat<<<NP, 256, 0, stream>>>(w_gate_in, b_gate_in, w_pre, b_pre,
                                     w_gate_out, b_gate_out, w_skip, b_skip,
                                     wcat, bcat);
  k_gemm_xproj<<<dim3(NP / 128, TB / 128), 256, 0, stream>>>(
      x, wcat, bcat, proj);
  k_prep<<<128, 256, 0, stream>>>(w_z, wzt);
  k_scan_a<<<(NCH - 1) * B_DIM * 16, 64, 0, stream>>>(
      proj, startw, ffm_a, ffm_b, carry, rstflag);
  k_scan_c<<<NCH * B_DIM * 16, 64, 0, stream>>>(
      proj, startw, state_re, state_im, ffm_a, ffm_b, carry, rstflag,
      zin, fstate);
  k_gemm_bt<2048><<<dim3(2, TB / 128), 256, 0, stream>>>(
      zin, wzt, b_z, zb, 256);
  k_out2<<<TB / 16, 256, 0, stream>>>(zb, proj, out);
}

// Round 9
// 220.616 us; speedup vs baseline: 5.4829x; 1.0370x over previous
//
#include <hip/hip_runtime.h>
#include <hip/hip_bf16.h>

#define T_DIM 1024
#define B_DIM 32
#define D_DIM 256
#define TRACE 64
#define CTX 16
#define OUT_DIM 256
#define TB (T_DIM * B_DIM)          // 32768 rows
#define KZ (2 * TRACE * CTX)        // 2048
#define NP 640                      // concat proj width
#define NCH 8                       // scan chunks
#define CHL 128                     // chunk length

typedef short short8 __attribute__((ext_vector_type(8)));
typedef float floatx4 __attribute__((ext_vector_type(4)));
typedef unsigned short ushortx4 __attribute__((ext_vector_type(4)));

__device__ __forceinline__ float bf2f(unsigned short u) {
  return __uint_as_float((unsigned int)u << 16);
}
__device__ __forceinline__ float sigm(float v) {
  return 1.f / (1.f + expf(-v));
}

// ---------------------------------------------------------------------------
// K0a: classify `start` buffer encoding from its byte pattern.
// ---------------------------------------------------------------------------
__global__ void k_start_detect(const unsigned char* __restrict__ s,
                               int* __restrict__ flag) {
  __shared__ int a1, a3, a4;
  if (threadIdx.x == 0) { a1 = 0; a3 = 0; a4 = 0; }
  __syncthreads();
  int l1 = 0, l3 = 0, l4 = 0;
  for (int i = threadIdx.x; i < 32768; i += 256) {
    unsigned char v = s[i];
    if (v) {
      int m4 = i & 3, m8 = i & 7;
      if (m4 == 1) l1 = 1;
      if (m4 == 3) l3 = 1;
      if (m8 == 4) l4 = 1;
    }
  }
  if (l1) atomicOr(&a1, 1);
  if (l3) atomicOr(&a3, 1);
  if (l4) atomicOr(&a4, 1);
  __syncthreads();
  if (threadIdx.x == 0) *flag = a1 ? 1 : (a3 ? 2 : (a4 ? 0 : 3));
}

__global__ void k_start_unpack(const unsigned char* __restrict__ s,
                               const int* __restrict__ flag,
                               int* __restrict__ out) {
  int i = blockIdx.x * 256 + threadIdx.x;   // 32768 total (128 blocks)
  int f = *flag;
  int v;
  if (f == 1)      v = s[i] != 0;
  else if (f == 2) v = reinterpret_cast<const float*>(s)[i] != 0.f;
  else if (f == 3) v = reinterpret_cast<const long long*>(s)[i] != 0;
  else             v = reinterpret_cast<const int*>(s)[i] != 0;
  out[i] = v;
}

// ---------------------------------------------------------------------------
// K0b: wzt[n][k'] = bf16(w_z[perm(k')][n]); zin K is permuted so (re,im) of a
// ctx are adjacent: k' = trace*32 + cx*2 + ri ; source k = trace*32 + ri*16 + cx
// ---------------------------------------------------------------------------
__global__ __launch_bounds__(256) void k_prep(
    const float* __restrict__ wz, __hip_bfloat16* __restrict__ wzt) {
  const int tk = blockIdx.x & 31;
  const int tn = blockIdx.x >> 5;
  const int k0 = tk * 64, n0 = tn * 64;
  __shared__ float sm[64][65];
  const int tid = threadIdx.x;
  for (int i = tid; i < 4096; i += 256) {
    int r = i >> 6, c = i & 63;
    sm[r][c] = wz[(size_t)(k0 + r) * 256 + n0 + c];
  }
  __syncthreads();
  for (int i = tid; i < 4096; i += 256) {
    int r = i >> 6, c = i & 63;   // r: n-within, c: k'-within (output)
    int src = (c & 0x20) | ((c & 1) << 4) | ((c >> 1) & 15);
    wzt[(size_t)(n0 + r) * 2048 + k0 + c] = __float2bfloat16(sm[src][r]);
  }
}

// ---------------------------------------------------------------------------
// K0c: wcat[n][k] = bf16 of transposed concat [w_gate_in|w_pre|w_gate_out|w_skip]
// ---------------------------------------------------------------------------
__global__ __launch_bounds__(256) void k_prep_cat(
    const float* __restrict__ wgi, const float* __restrict__ bgi,
    const float* __restrict__ wpr, const float* __restrict__ bpr,
    const float* __restrict__ wgo, const float* __restrict__ bgo,
    const float* __restrict__ wsk, const float* __restrict__ bsk,
    __hip_bfloat16* __restrict__ wcat, float* __restrict__ bcat) {
  const int n = blockIdx.x, k = threadIdx.x;
  float v, bv;
  if (n < 64)        { v = wgi[k * 64 + n];          bv = bgi[n]; }
  else if (n < 128)  { v = wpr[k * 64 + (n - 64)];   bv = bpr[n - 64]; }
  else if (n < 384)  { v = wgo[k * 256 + (n - 128)]; bv = bgo[n - 128]; }
  else               { v = wsk[k * 256 + (n - 384)]; bv = bsk[n - 384]; }
  wcat[(size_t)n * 256 + k] = __float2bfloat16(v);
  if (k == 0) bcat[n] = bv;
}

// ---------------------------------------------------------------------------
// Proj GEMM: proj = bf16( f32(x) @ wcat^T + bcat ). M=32768, K=256, N=640.
// ---------------------------------------------------------------------------
__global__ __launch_bounds__(256) void k_gemm_xproj(
    const float* __restrict__ A, const __hip_bfloat16* __restrict__ Bm,
    const float* __restrict__ bias, __hip_bfloat16* __restrict__ C) {
  const int r0 = blockIdx.y * 128;
  const int n0 = blockIdx.x * 128;
  const int tid = threadIdx.x;
  const int l = tid & 63;
  const int wid = tid >> 6;
  const int wr = wid >> 1;
  const int wc = wid & 1;

  __shared__ __align__(16) char ldsA[16384];
  __shared__ __align__(16) char ldsB[16384];

  floatx4 acc[4][4];
#pragma unroll
  for (int m = 0; m < 4; ++m)
#pragma unroll
    for (int n = 0; n < 4; ++n) acc[m][n] = (floatx4)0.f;

  int aoff[4][2], boff[4][2];
#pragma unroll
  for (int m = 0; m < 4; ++m) {
    int row = wr * 64 + m * 16 + (l & 15);
#pragma unroll
    for (int ks = 0; ks < 2; ++ks) {
      int byte = row * 128 + ks * 64 + (l >> 4) * 16;
      aoff[m][ks] = byte ^ ((row & 7) << 4);
    }
    int col = wc * 64 + m * 16 + (l & 15);
#pragma unroll
    for (int ks = 0; ks < 2; ++ks) {
      int byte = col * 128 + ks * 64 + (l >> 4) * 16;
      boff[m][ks] = byte ^ ((col & 7) << 4);
    }
  }

  for (int kt = 0; kt < 256; kt += 64) {
#pragma unroll
    for (int i = 0; i < 4; ++i) {
      int c = tid + i * 256;          // [0,1024): 128 rows x 8 chunks
      int row = c >> 3, kg = c & 7;
      int byte = (row * 128 + kg * 16) ^ ((row & 7) << 4);
      const float* ap = A + (size_t)(r0 + row) * 256 + kt + kg * 8;
      float4 a0 = *reinterpret_cast<const float4*>(ap);
      float4 a1 = *reinterpret_cast<const float4*>(ap + 4);
      unsigned short u[8];
      u[0] = __bfloat16_as_ushort(__float2bfloat16(a0.x));
      u[1] = __bfloat16_as_ushort(__float2bfloat16(a0.y));
      u[2] = __bfloat16_as_ushort(__float2bfloat16(a0.z));
      u[3] = __bfloat16_as_ushort(__float2bfloat16(a0.w));
      u[4] = __bfloat16_as_ushort(__float2bfloat16(a1.x));
      u[5] = __bfloat16_as_ushort(__float2bfloat16(a1.y));
      u[6] = __bfloat16_as_ushort(__float2bfloat16(a1.z));
      u[7] = __bfloat16_as_ushort(__float2bfloat16(a1.w));
      *reinterpret_cast<uint4*>(ldsA + byte) = *reinterpret_cast<uint4*>(u);
      uint4 vb = *reinterpret_cast<const uint4*>(
          Bm + (size_t)(n0 + row) * 256 + kt + kg * 8);
      *reinterpret_cast<uint4*>(ldsB + byte) = vb;
    }
    __syncthreads();
#pragma unroll
    for (int ks = 0; ks < 2; ++ks) {
      short8 a[4], b[4];
#pragma unroll
      for (int m = 0; m < 4; ++m)
        a[m] = *reinterpret_cast<const short8*>(ldsA + aoff[m][ks]);
#pragma unroll
      for (int n = 0; n < 4; ++n)
        b[n] = *reinterpret_cast<const short8*>(ldsB + boff[n][ks]);
#pragma unroll
      for (int m = 0; m < 4; ++m)
#pragma unroll
        for (int n = 0; n < 4; ++n)
          acc[m][n] = __builtin_amdgcn_mfma_f32_16x16x32_bf16(
              a[m], b[n], acc[m][n], 0, 0, 0);
    }
    __syncthreads();
  }

#pragma unroll
  for (int m = 0; m < 4; ++m) {
#pragma unroll
    for (int n = 0; n < 4; ++n) {
      int gc = n0 + wc * 64 + n * 16 + (l & 15);
      float bzv = bias[gc];
#pragma unroll
      for (int j = 0; j < 4; ++j) {
        int gr = r0 + wr * 64 + m * 16 + (l >> 4) * 4 + j;
        C[(size_t)gr * NP + gc] = __float2bfloat16(acc[m][n][j] + bzv);
      }
    }
  }
}

// ---------------------------------------------------------------------------
// Fused z-GEMM + LayerNorm epilogue.
// z = zin @ wzt^T + bz ; y = z*sigmoid(go_pre) ; out = LN(y) + ps*(1-go)
// Tile 128M x 256N (full N), 4 waves, each wave owns 32 COMPLETE rows
// (2 m-frags x 16 n-frags, acc 128 VGPR) -> LN is wave-local shuffles.
// Single-buffered swizzled LDS: A 16KB + B 32KB.
// ---------------------------------------------------------------------------
__global__ __launch_bounds__(256) void k_zgemm_ln(
    const __hip_bfloat16* __restrict__ zin, const __hip_bfloat16* __restrict__ wzt,
    const float* __restrict__ bz, const __hip_bfloat16* __restrict__ proj,
    float* __restrict__ out) {
  const int r0 = blockIdx.x * 128;
  const int tid = threadIdx.x;
  const int l = tid & 63;
  const int wid = tid >> 6;          // 0..3, rows [wid*32, wid*32+32)

  __shared__ __align__(16) char ldsA[16384];   // [128][64] bf16 swz
  __shared__ __align__(16) char ldsB[32768];   // [256][64] bf16 swz

  floatx4 acc[2][16];
#pragma unroll
  for (int m = 0; m < 2; ++m)
#pragma unroll
    for (int n = 0; n < 16; ++n) acc[m][n] = (floatx4)0.f;

  int aoff[2][2], boff[16][2];
#pragma unroll
  for (int m = 0; m < 2; ++m) {
    int row = wid * 32 + m * 16 + (l & 15);
#pragma unroll
    for (int ks = 0; ks < 2; ++ks) {
      int byte = row * 128 + ks * 64 + (l >> 4) * 16;
      aoff[m][ks] = byte ^ ((row & 7) << 4);
    }
  }
#pragma unroll
  for (int n = 0; n < 16; ++n) {
    int col = n * 16 + (l & 15);
#pragma unroll
    for (int ks = 0; ks < 2; ++ks) {
      int byte = col * 128 + ks * 64 + (l >> 4) * 16;
      boff[n][ks] = byte ^ ((col & 7) << 4);
    }
  }

  for (int kt = 0; kt < KZ; kt += 64) {
    // stage A: 128 rows x 8 chunks = 1024
#pragma unroll
    for (int i = 0; i < 4; ++i) {
      int c = tid + i * 256;
      int row = c >> 3, kg = c & 7;
      int byte = (row * 128 + kg * 16) ^ ((row & 7) << 4);
      uint4 va = *reinterpret_cast<const uint4*>(
          zin + (size_t)(r0 + row) * KZ + kt + kg * 8);
      *reinterpret_cast<uint4*>(ldsA + byte) = va;
    }
    // stage B: 256 rows x 8 chunks = 2048
#pragma unroll
    for (int i = 0; i < 8; ++i) {
      int c = tid + i * 256;
      int row = c >> 3, kg = c & 7;
      int byte = (row * 128 + kg * 16) ^ ((row & 7) << 4);
      uint4 vb = *reinterpret_cast<const uint4*>(
          wzt + (size_t)row * KZ + kt + kg * 8);
      *reinterpret_cast<uint4*>(ldsB + byte) = vb;
    }
    __syncthreads();
#pragma unroll
    for (int ks = 0; ks < 2; ++ks) {
      short8 a0 = *reinterpret_cast<const short8*>(ldsA + aoff[0][ks]);
      short8 a1 = *reinterpret_cast<const short8*>(ldsA + aoff[1][ks]);
#pragma unroll
      for (int n = 0; n < 16; ++n) {
        short8 b = *reinterpret_cast<const short8*>(ldsB + boff[n][ks]);
        acc[0][n] = __builtin_amdgcn_mfma_f32_16x16x32_bf16(a0, b, acc[0][n], 0, 0, 0);
        acc[1][n] = __builtin_amdgcn_mfma_f32_16x16x32_bf16(a1, b, acc[1][n], 0, 0, 0);
      }
    }
    __syncthreads();
  }

  // bias per n-frag col (col = n*16 + (l&15))
  float bzv[16];
#pragma unroll
  for (int n = 0; n < 16; ++n) bzv[n] = bz[n * 16 + (l & 15)];

  // epilogue: rows wid*32 + m*16 + (l>>4)*4 + j, full 256 cols in-wave
#pragma unroll
  for (int m = 0; m < 2; ++m) {
#pragma unroll
    for (int j = 0; j < 4; ++j) {
      int gr = r0 + wid * 32 + m * 16 + (l >> 4) * 4 + j;
      const __hip_bfloat16* prow = proj + (size_t)gr * NP;
      float y[16], go[16], ps[16];
      float s1 = 0.f, s2 = 0.f;
#pragma unroll
      for (int n = 0; n < 16; ++n) {
        int col = n * 16 + (l & 15);
        go[n] = sigm(__bfloat162float(prow[128 + col]));
        ps[n] = __bfloat162float(prow[384 + col]);
        float zv = acc[m][n][j] + bzv[n];
        y[n] = zv * go[n];
        s1 += y[n];
        s2 += y[n] * y[n];
      }
#pragma unroll
      for (int off = 8; off > 0; off >>= 1) {
        s1 += __shfl_xor(s1, off);
        s2 += __shfl_xor(s2, off);
      }
      float mu = s1 * (1.f / 256.f);
      float var = s2 * (1.f / 256.f) - mu * mu;
      float rs = rsqrtf(var + 1e-6f);
#pragma unroll
      for (int n = 0; n < 16; ++n) {
        int col = n * 16 + (l & 15);
        out[(size_t)gr * 256 + col] = (y[n] - mu) * rs + ps[n] * (1.f - go[n]);
      }
    }
  }
}

// ---------------------------------------------------------------------------
// K2a: per-chunk local scan -> carry s_c (complex) per chain; rst_any per
// (chunk,b). block = (chunk<7, b, tg); 64 threads = (tl 0..3, cx 0..15).
// ---------------------------------------------------------------------------
__global__ __launch_bounds__(64) void k_scan_a(
    const __hip_bfloat16* __restrict__ proj, const int* __restrict__ startw,
    const float* __restrict__ ffm_a, const float* __restrict__ ffm_b,
    float2* __restrict__ carry, int* __restrict__ rstflag) {
  const int c  = blockIdx.x >> 9;        // 0..6
  const int bb = (blockIdx.x >> 4) & 31;
  const int tg = blockIdx.x & 15;
  const int tid = threadIdx.x;
  const int tl = tid >> 4, cx = tid & 15;
  const int trace = tg * 4 + tl;
  const int t0 = c * CHL;
  __shared__ float gs[CHL * 4];
  __shared__ int ss[CHL];
  for (int t = tid; t < CHL; t += 64) {
    size_t base = ((size_t)(t0 + t) * B_DIM + bb) * NP + tg * 4;
    ushortx4 pg4 = *reinterpret_cast<const ushortx4*>(proj + base);
    ushortx4 pp4 = *reinterpret_cast<const ushortx4*>(proj + base + 64);
    float4 o;
    o.x = bf2f(pp4[0]) * sigm(bf2f(pg4[0]));
    o.y = bf2f(pp4[1]) * sigm(bf2f(pg4[1]));
    o.z = bf2f(pp4[2]) * sigm(bf2f(pg4[2]));
    o.w = bf2f(pp4[3]) * sigm(bf2f(pg4[3]));
    *reinterpret_cast<float4*>(&gs[t * 4]) = o;
    ss[t] = startw[(t0 + t) * B_DIM + bb];
  }
  __syncthreads();

  int lrst = ss[tid] | ss[tid + 64];
  int any = __any(lrst != 0);
  if (tid == 0 && tg == 0) rstflag[c * B_DIM + bb] = any;

  float decay = expf(-fabsf(ffm_a[trace]));
  float th = ffm_b[cx];
  float cr = decay * cosf(th);
  float ci = decay * sinf(th);
  float sr = 0.f, si = 0.f;
  for (int t = 0; t < CHL; ++t) {
    float g = gs[t * 4 + tl];
    int rst = ss[t];
    float nr = fmaf(sr, cr, fmaf(-si, ci, g));
    float ni = fmaf(sr, ci, si * cr);
    sr = rst ? g : nr;
    si = rst ? 0.f : ni;
  }
  carry[((size_t)(c * B_DIM + bb) * TRACE + trace) * CTX + cx] =
      make_float2(sr, si);
}

// ---------------------------------------------------------------------------
// K2c: combine carries -> chunk-start state, then scan chunk writing zin
// (packed re|im<<16 uint per (trace,cx)). chunk 7 writes fstate (real).
// ---------------------------------------------------------------------------
__global__ __launch_bounds__(64) void k_scan_c(
    const __hip_bfloat16* __restrict__ proj, const int* __restrict__ startw,
    const float* __restrict__ state_re, const float* __restrict__ state_im,
    const float* __restrict__ ffm_a, const float* __restrict__ ffm_b,
    const float2* __restrict__ carry, const int* __restrict__ rstflag,
    __hip_bfloat16* __restrict__ zin, float* __restrict__ fstate) {
  const int c  = blockIdx.x >> 9;        // 0..7
  const int bb = (blockIdx.x >> 4) & 31;
  const int tg = blockIdx.x & 15;
  const int tid = threadIdx.x;
  const int tl = tid >> 4, cx = tid & 15;
  const int trace = tg * 4 + tl;
  const int t0 = c * CHL;
  __shared__ float gs[CHL * 4];
  __shared__ int ss[CHL];
  for (int t = tid; t < CHL; t += 64) {
    size_t base = ((size_t)(t0 + t) * B_DIM + bb) * NP + tg * 4;
    ushortx4 pg4 = *reinterpret_cast<const ushortx4*>(proj + base);
    ushortx4 pp4 = *reinterpret_cast<const ushortx4*>(proj + base + 64);
    float4 o;
    o.x = bf2f(pp4[0]) * sigm(bf2f(pg4[0]));
    o.y = bf2f(pp4[1]) * sigm(bf2f(pg4[1]));
    o.z = bf2f(pp4[2]) * sigm(bf2f(pg4[2]));
    o.w = bf2f(pp4[3]) * sigm(bf2f(pg4[3]));
    *reinterpret_cast<float4*>(&gs[t * 4]) = o;
    ss[t] = startw[(t0 + t) * B_DIM + bb];
  }
  __syncthreads();

  float decay = expf(-fabsf(ffm_a[trace]));
  float th = ffm_b[cx];
  float cr = decay * cosf(th);
  float ci = decay * sinf(th);

  float pr = cr, pi = ci;
#pragma unroll
  for (int q = 0; q < 7; ++q) {
    float nr = pr * pr - pi * pi;
    float ni = 2.f * pr * pi;
    pr = nr; pi = ni;
  }

  const int chain = (bb * TRACE + trace) * CTX + cx;
  float sr = state_re[chain];
  float si = state_im[chain];
  for (int j = 0; j < c; ++j) {
    float2 cj = carry[((size_t)(j * B_DIM + bb) * TRACE + trace) * CTX + cx];
    if (rstflag[j * B_DIM + bb]) {
      sr = cj.x; si = cj.y;
    } else {
      float nsr = fmaf(pr, sr, fmaf(-pi, si, cj.x));
      float nsi = fmaf(pr, si, fmaf(pi, sr, cj.y));
      sr = nsr; si = nsi;
    }
  }

  const size_t zbase = (size_t)trace * 32 + cx * 2;
  for (int t = 0; t < CHL; ++t) {
    float g = gs[t * 4 + tl];
    int rst = ss[t];
    float nr = fmaf(sr, cr, fmaf(-si, ci, g));
    float ni = fmaf(sr, ci, si * cr);
    sr = rst ? g : nr;
    si = rst ? 0.f : ni;
    unsigned int u = (unsigned int)__bfloat16_as_ushort(__float2bfloat16(sr)) |
                     ((unsigned int)__bfloat16_as_ushort(__float2bfloat16(si)) << 16);
    *reinterpret_cast<unsigned int*>(
        zin + ((size_t)(t0 + t) * B_DIM + bb) * KZ + zbase) = u;
  }
  if (c == NCH - 1) fstate[chain] = sr;
}

extern "C" void kernel_launch(void* const* d_in, const int* in_sizes, int n_in,
                              void* d_out, int out_size, void* d_ws, size_t ws_size,
                              hipStream_t stream) {
  const float* x         = (const float*)d_in[0];
  const unsigned char* start_raw = (const unsigned char*)d_in[1];
  const float* state_re  = (const float*)d_in[2];
  const float* state_im  = (const float*)d_in[3];
  const float* w_gate_in = (const float*)d_in[4];
  const float* b_gate_in = (const float*)d_in[5];
  const float* w_pre     = (const float*)d_in[6];
  const float* b_pre     = (const float*)d_in[7];
  const float* w_z       = (const float*)d_in[8];
  const float* b_z       = (const float*)d_in[9];
  const float* w_gate_out= (const float*)d_in[10];
  const float* b_gate_out= (const float*)d_in[11];
  const float* w_skip    = (const float*)d_in[12];
  const float* b_skip    = (const float*)d_in[13];
  const float* ffm_a     = (const float*)d_in[14];
  const float* ffm_b     = (const float*)d_in[15];

  // workspace layout
  char* ws = (char*)d_ws;
  int* flag     = (int*)ws;                                   // [0, 4KB)
  int* startw   = (int*)(ws + 4096);                          // [4KB, 132KB)
  int* rstflag  = (int*)(ws + (132 << 10));                   // [132KB, 133KB)
  float* bcat   = (float*)(ws + (160 << 10));                 // [160KB, 163KB)
  __hip_bfloat16* wcat =
      (__hip_bfloat16*)(ws + (256 << 10));                    // [256KB, 576KB)
  __hip_bfloat16* wzt =
      (__hip_bfloat16*)(ws + ((size_t)1 << 20));              // [1MB, 2MB)
  float2* carry = (float2*)(ws + ((size_t)2 << 20));          // [2MB, 4MB)
  __hip_bfloat16* proj =
      (__hip_bfloat16*)(ws + ((size_t)4 << 20));              // [4MB, 44MB)
  __hip_bfloat16* zin =
      (__hip_bfloat16*)(ws + ((size_t)60 << 20));             // [60MB, 188MB)

  float* fstate = (float*)d_out;                    // real(final_state), 32768
  float* out    = (float*)d_out + B_DIM * TRACE * CTX;

  k_start_detect<<<1, 256, 0, stream>>>(start_raw, flag);
  k_start_unpack<<<TB / 256, 256, 0, stream>>>(start_raw, flag, startw);
  k_prep_cat<<<NP, 256, 0, stream>>>(w_gate_in, b_gate_in, w_pre, b_pre,
                                     w_gate_out, b_gate_out, w_skip, b_skip,
                                     wcat, bcat);
  k_gemm_xproj<<<dim3(NP / 128, TB / 128), 256, 0, stream>>>(
      x, wcat, bcat, proj);
  k_prep<<<128, 256, 0, stream>>>(w_z, wzt);
  k_scan_a<<<(NCH - 1) * B_DIM * 16, 64, 0, stream>>>(
      proj, startw, ffm_a, ffm_b, carry, rstflag);
  k_scan_c<<<NCH * B_DIM * 16, 64, 0, stream>>>(
      proj, startw, state_re, state_im, ffm_a, ffm_b, carry, rstflag,
      zin, fstate);
  k_zgemm_ln<<<TB / 128, 256, 0, stream>>>(zin, wzt, b_z, proj, out);
}

// Round 10
// 191.254 us; speedup vs baseline: 6.3247x; 1.1535x over previous
//
#include <hip/hip_runtime.h>
#include <hip/hip_bf16.h>

#define T_DIM 1024
#define B_DIM 32
#define D_DIM 256
#define TRACE 64
#define CTX 16
#define OUT_DIM 256
#define TB (T_DIM * B_DIM)          // 32768 rows
#define KZ (2 * TRACE * CTX)        // 2048
#define NP 640                      // concat proj width
#define NCH 8                       // scan chunks
#define CHL 128                     // chunk length

typedef short short8 __attribute__((ext_vector_type(8)));
typedef float floatx4 __attribute__((ext_vector_type(4)));
typedef unsigned short ushortx4 __attribute__((ext_vector_type(4)));

__device__ __forceinline__ float bf2f(unsigned short u) {
  return __uint_as_float((unsigned int)u << 16);
}
__device__ __forceinline__ float sigm(float v) {
  return 1.f / (1.f + expf(-v));
}

// ---------------------------------------------------------------------------
// K0a: classify `start` buffer encoding from its byte pattern.
// ---------------------------------------------------------------------------
__global__ void k_start_detect(const unsigned char* __restrict__ s,
                               int* __restrict__ flag) {
  __shared__ int a1, a3, a4;
  if (threadIdx.x == 0) { a1 = 0; a3 = 0; a4 = 0; }
  __syncthreads();
  int l1 = 0, l3 = 0, l4 = 0;
  for (int i = threadIdx.x; i < 32768; i += 256) {
    unsigned char v = s[i];
    if (v) {
      int m4 = i & 3, m8 = i & 7;
      if (m4 == 1) l1 = 1;
      if (m4 == 3) l3 = 1;
      if (m8 == 4) l4 = 1;
    }
  }
  if (l1) atomicOr(&a1, 1);
  if (l3) atomicOr(&a3, 1);
  if (l4) atomicOr(&a4, 1);
  __syncthreads();
  if (threadIdx.x == 0) *flag = a1 ? 1 : (a3 ? 2 : (a4 ? 0 : 3));
}

__global__ void k_start_unpack(const unsigned char* __restrict__ s,
                               const int* __restrict__ flag,
                               int* __restrict__ out) {
  int i = blockIdx.x * 256 + threadIdx.x;   // 32768 total (128 blocks)
  int f = *flag;
  int v;
  if (f == 1)      v = s[i] != 0;
  else if (f == 2) v = reinterpret_cast<const float*>(s)[i] != 0.f;
  else if (f == 3) v = reinterpret_cast<const long long*>(s)[i] != 0;
  else             v = reinterpret_cast<const int*>(s)[i] != 0;
  out[i] = v;
}

// ---------------------------------------------------------------------------
// K0b: wzt[n][k'] = bf16(w_z[perm(k')][n]); zin K is permuted so (re,im) of a
// ctx are adjacent: k' = trace*32 + cx*2 + ri ; source k = trace*32 + ri*16 + cx
// ---------------------------------------------------------------------------
__global__ __launch_bounds__(256) void k_prep(
    const float* __restrict__ wz, __hip_bfloat16* __restrict__ wzt) {
  const int tk = blockIdx.x & 31;
  const int tn = blockIdx.x >> 5;
  const int k0 = tk * 64, n0 = tn * 64;
  __shared__ float sm[64][65];
  const int tid = threadIdx.x;
  for (int i = tid; i < 4096; i += 256) {
    int r = i >> 6, c = i & 63;
    sm[r][c] = wz[(size_t)(k0 + r) * 256 + n0 + c];
  }
  __syncthreads();
  for (int i = tid; i < 4096; i += 256) {
    int r = i >> 6, c = i & 63;   // r: n-within, c: k'-within (output)
    int src = (c & 0x20) | ((c & 1) << 4) | ((c >> 1) & 15);
    wzt[(size_t)(n0 + r) * 2048 + k0 + c] = __float2bfloat16(sm[src][r]);
  }
}

// ---------------------------------------------------------------------------
// K0c: wcat[n][k] = bf16 of transposed concat [w_gate_in|w_pre|w_gate_out|w_skip]
// ---------------------------------------------------------------------------
__global__ __launch_bounds__(256) void k_prep_cat(
    const float* __restrict__ wgi, const float* __restrict__ bgi,
    const float* __restrict__ wpr, const float* __restrict__ bpr,
    const float* __restrict__ wgo, const float* __restrict__ bgo,
    const float* __restrict__ wsk, const float* __restrict__ bsk,
    __hip_bfloat16* __restrict__ wcat, float* __restrict__ bcat) {
  const int n = blockIdx.x, k = threadIdx.x;
  float v, bv;
  if (n < 64)        { v = wgi[k * 64 + n];          bv = bgi[n]; }
  else if (n < 128)  { v = wpr[k * 64 + (n - 64)];   bv = bpr[n - 64]; }
  else if (n < 384)  { v = wgo[k * 256 + (n - 128)]; bv = bgo[n - 128]; }
  else               { v = wsk[k * 256 + (n - 384)]; bv = bsk[n - 384]; }
  wcat[(size_t)n * 256 + k] = __float2bfloat16(v);
  if (k == 0) bcat[n] = bv;
}

// ---------------------------------------------------------------------------
// Proj GEMM: proj = bf16( f32(x) @ wcat^T + bcat ). M=32768, K=256, N=640.
// ---------------------------------------------------------------------------
__global__ __launch_bounds__(256) void k_gemm_xproj(
    const float* __restrict__ A, const __hip_bfloat16* __restrict__ Bm,
    const float* __restrict__ bias, __hip_bfloat16* __restrict__ C) {
  const int r0 = blockIdx.y * 128;
  const int n0 = blockIdx.x * 128;
  const int tid = threadIdx.x;
  const int l = tid & 63;
  const int wid = tid >> 6;
  const int wr = wid >> 1;
  const int wc = wid & 1;

  __shared__ __align__(16) char ldsA[16384];
  __shared__ __align__(16) char ldsB[16384];

  floatx4 acc[4][4];
#pragma unroll
  for (int m = 0; m < 4; ++m)
#pragma unroll
    for (int n = 0; n < 4; ++n) acc[m][n] = (floatx4)0.f;

  int aoff[4][2], boff[4][2];
#pragma unroll
  for (int m = 0; m < 4; ++m) {
    int row = wr * 64 + m * 16 + (l & 15);
#pragma unroll
    for (int ks = 0; ks < 2; ++ks) {
      int byte = row * 128 + ks * 64 + (l >> 4) * 16;
      aoff[m][ks] = byte ^ ((row & 7) << 4);
    }
    int col = wc * 64 + m * 16 + (l & 15);
#pragma unroll
    for (int ks = 0; ks < 2; ++ks) {
      int byte = col * 128 + ks * 64 + (l >> 4) * 16;
      boff[m][ks] = byte ^ ((col & 7) << 4);
    }
  }

  for (int kt = 0; kt < 256; kt += 64) {
#pragma unroll
    for (int i = 0; i < 4; ++i) {
      int c = tid + i * 256;          // [0,1024): 128 rows x 8 chunks
      int row = c >> 3, kg = c & 7;
      int byte = (row * 128 + kg * 16) ^ ((row & 7) << 4);
      const float* ap = A + (size_t)(r0 + row) * 256 + kt + kg * 8;
      float4 a0 = *reinterpret_cast<const float4*>(ap);
      float4 a1 = *reinterpret_cast<const float4*>(ap + 4);
      unsigned short u[8];
      u[0] = __bfloat16_as_ushort(__float2bfloat16(a0.x));
      u[1] = __bfloat16_as_ushort(__float2bfloat16(a0.y));
      u[2] = __bfloat16_as_ushort(__float2bfloat16(a0.z));
      u[3] = __bfloat16_as_ushort(__float2bfloat16(a0.w));
      u[4] = __bfloat16_as_ushort(__float2bfloat16(a1.x));
      u[5] = __bfloat16_as_ushort(__float2bfloat16(a1.y));
      u[6] = __bfloat16_as_ushort(__float2bfloat16(a1.z));
      u[7] = __bfloat16_as_ushort(__float2bfloat16(a1.w));
      *reinterpret_cast<uint4*>(ldsA + byte) = *reinterpret_cast<uint4*>(u);
      uint4 vb = *reinterpret_cast<const uint4*>(
          Bm + (size_t)(n0 + row) * 256 + kt + kg * 8);
      *reinterpret_cast<uint4*>(ldsB + byte) = vb;
    }
    __syncthreads();
#pragma unroll
    for (int ks = 0; ks < 2; ++ks) {
      short8 a[4], b[4];
#pragma unroll
      for (int m = 0; m < 4; ++m)
        a[m] = *reinterpret_cast<const short8*>(ldsA + aoff[m][ks]);
#pragma unroll
      for (int n = 0; n < 4; ++n)
        b[n] = *reinterpret_cast<const short8*>(ldsB + boff[n][ks]);
#pragma unroll
      for (int m = 0; m < 4; ++m)
#pragma unroll
        for (int n = 0; n < 4; ++n)
          acc[m][n] = __builtin_amdgcn_mfma_f32_16x16x32_bf16(
              a[m], b[n], acc[m][n], 0, 0, 0);
    }
    __syncthreads();
  }

#pragma unroll
  for (int m = 0; m < 4; ++m) {
#pragma unroll
    for (int n = 0; n < 4; ++n) {
      int gc = n0 + wc * 64 + n * 16 + (l & 15);
      float bzv = bias[gc];
#pragma unroll
      for (int j = 0; j < 4; ++j) {
        int gr = r0 + wr * 64 + m * 16 + (l >> 4) * 4 + j;
        C[(size_t)gr * NP + gc] = __float2bfloat16(acc[m][n][j] + bzv);
      }
    }
  }
}

// ---------------------------------------------------------------------------
// Fused z-GEMM + LayerNorm epilogue, v2 (occupancy-fixed).
// Tile 64M x 256N, grid 512 blocks (2+/CU). 4 waves split N: wave w owns
// cols [w*64, w*64+64) for all 64 rows (4m x 4n frags, 64 acc VGPR).
// LN: 16-lane shuffle reduce -> LDS red[64][4] cross-wave combine.
// ---------------------------------------------------------------------------
__global__ __launch_bounds__(256, 2) void k_zgemm_ln(
    const __hip_bfloat16* __restrict__ zin, const __hip_bfloat16* __restrict__ wzt,
    const float* __restrict__ bz, const __hip_bfloat16* __restrict__ proj,
    float* __restrict__ out) {
  const int r0 = blockIdx.x * 64;
  const int tid = threadIdx.x;
  const int l = tid & 63;
  const int w = tid >> 6;            // wave id = N-slice

  __shared__ __align__(16) char ldsA[8192];    // [64][64] bf16 swz
  __shared__ __align__(16) char ldsB[32768];   // [256][64] bf16 swz
  __shared__ float red1[64][4], red2[64][4];

  floatx4 acc[4][4];
#pragma unroll
  for (int m = 0; m < 4; ++m)
#pragma unroll
    for (int n = 0; n < 4; ++n) acc[m][n] = (floatx4)0.f;

  int aoff[4][2], boff[4][2];
#pragma unroll
  for (int m = 0; m < 4; ++m) {
    int row = m * 16 + (l & 15);
#pragma unroll
    for (int ks = 0; ks < 2; ++ks) {
      int byte = row * 128 + ks * 64 + (l >> 4) * 16;
      aoff[m][ks] = byte ^ ((row & 7) << 4);
    }
  }
#pragma unroll
  for (int n = 0; n < 4; ++n) {
    int col = w * 64 + n * 16 + (l & 15);
#pragma unroll
    for (int ks = 0; ks < 2; ++ks) {
      int byte = col * 128 + ks * 64 + (l >> 4) * 16;
      boff[n][ks] = byte ^ ((col & 7) << 4);
    }
  }

  for (int kt = 0; kt < KZ; kt += 64) {
    // stage A: 64 rows x 8 chunks = 512
#pragma unroll
    for (int i = 0; i < 2; ++i) {
      int c = tid + i * 256;
      int row = c >> 3, kg = c & 7;
      int byte = (row * 128 + kg * 16) ^ ((row & 7) << 4);
      uint4 va = *reinterpret_cast<const uint4*>(
          zin + (size_t)(r0 + row) * KZ + kt + kg * 8);
      *reinterpret_cast<uint4*>(ldsA + byte) = va;
    }
    // stage B: 256 rows x 8 chunks = 2048
#pragma unroll
    for (int i = 0; i < 8; ++i) {
      int c = tid + i * 256;
      int row = c >> 3, kg = c & 7;
      int byte = (row * 128 + kg * 16) ^ ((row & 7) << 4);
      uint4 vb = *reinterpret_cast<const uint4*>(
          wzt + (size_t)row * KZ + kt + kg * 8);
      *reinterpret_cast<uint4*>(ldsB + byte) = vb;
    }
    __syncthreads();
#pragma unroll
    for (int ks = 0; ks < 2; ++ks) {
      short8 a[4], b[4];
#pragma unroll
      for (int m = 0; m < 4; ++m)
        a[m] = *reinterpret_cast<const short8*>(ldsA + aoff[m][ks]);
#pragma unroll
      for (int n = 0; n < 4; ++n)
        b[n] = *reinterpret_cast<const short8*>(ldsB + boff[n][ks]);
#pragma unroll
      for (int m = 0; m < 4; ++m)
#pragma unroll
        for (int n = 0; n < 4; ++n)
          acc[m][n] = __builtin_amdgcn_mfma_f32_16x16x32_bf16(
              a[m], b[n], acc[m][n], 0, 0, 0);
    }
    __syncthreads();
  }

  float bzv[4];
#pragma unroll
  for (int n = 0; n < 4; ++n) bzv[n] = bz[w * 64 + n * 16 + (l & 15)];

  // phase 1: y in-place into acc, q = ps*(1-go), wave-local partial sums
  float q[4][4][4];
#pragma unroll
  for (int m = 0; m < 4; ++m) {
#pragma unroll
    for (int j = 0; j < 4; ++j) {
      int row = m * 16 + (l >> 4) * 4 + j;
      const __hip_bfloat16* prow = proj + (size_t)(r0 + row) * NP;
      float s1 = 0.f, s2 = 0.f;
#pragma unroll
      for (int n = 0; n < 4; ++n) {
        int col = w * 64 + n * 16 + (l & 15);
        float go = sigm(__bfloat162float(prow[128 + col]));
        float ps = __bfloat162float(prow[384 + col]);
        float y = (acc[m][n][j] + bzv[n]) * go;
        acc[m][n][j] = y;
        q[m][n][j] = ps * (1.f - go);
        s1 += y;
        s2 += y * y;
      }
#pragma unroll
      for (int off = 8; off > 0; off >>= 1) {
        s1 += __shfl_xor(s1, off);
        s2 += __shfl_xor(s2, off);
      }
      if ((l & 15) == 0) { red1[row][w] = s1; red2[row][w] = s2; }
    }
  }
  __syncthreads();

  // phase 2: combine cross-wave sums, normalize, write out
#pragma unroll
  for (int m = 0; m < 4; ++m) {
#pragma unroll
    for (int j = 0; j < 4; ++j) {
      int row = m * 16 + (l >> 4) * 4 + j;
      int gr = r0 + row;
      float t1 = red1[row][0] + red1[row][1] + red1[row][2] + red1[row][3];
      float t2 = red2[row][0] + red2[row][1] + red2[row][2] + red2[row][3];
      float mu = t1 * (1.f / 256.f);
      float var = t2 * (1.f / 256.f) - mu * mu;
      float rs = rsqrtf(var + 1e-6f);
#pragma unroll
      for (int n = 0; n < 4; ++n) {
        int col = w * 64 + n * 16 + (l & 15);
        out[(size_t)gr * 256 + col] = (acc[m][n][j] - mu) * rs + q[m][n][j];
      }
    }
  }
}

// ---------------------------------------------------------------------------
// K2a: per-chunk local scan -> carry s_c (complex) per chain; rst_any per
// (chunk,b). block = (chunk<7, b, tg); 64 threads = (tl 0..3, cx 0..15).
// ---------------------------------------------------------------------------
__global__ __launch_bounds__(64) void k_scan_a(
    const __hip_bfloat16* __restrict__ proj, const int* __restrict__ startw,
    const float* __restrict__ ffm_a, const float* __restrict__ ffm_b,
    float2* __restrict__ carry, int* __restrict__ rstflag) {
  const int c  = blockIdx.x >> 9;        // 0..6
  const int bb = (blockIdx.x >> 4) & 31;
  const int tg = blockIdx.x & 15;
  const int tid = threadIdx.x;
  const int tl = tid >> 4, cx = tid & 15;
  const int trace = tg * 4 + tl;
  const int t0 = c * CHL;
  __shared__ float gs[CHL * 4];
  __shared__ int ss[CHL];
  for (int t = tid; t < CHL; t += 64) {
    size_t base = ((size_t)(t0 + t) * B_DIM + bb) * NP + tg * 4;
    ushortx4 pg4 = *reinterpret_cast<const ushortx4*>(proj + base);
    ushortx4 pp4 = *reinterpret_cast<const ushortx4*>(proj + base + 64);
    float4 o;
    o.x = bf2f(pp4[0]) * sigm(bf2f(pg4[0]));
    o.y = bf2f(pp4[1]) * sigm(bf2f(pg4[1]));
    o.z = bf2f(pp4[2]) * sigm(bf2f(pg4[2]));
    o.w = bf2f(pp4[3]) * sigm(bf2f(pg4[3]));
    *reinterpret_cast<float4*>(&gs[t * 4]) = o;
    ss[t] = startw[(t0 + t) * B_DIM + bb];
  }
  __syncthreads();

  int lrst = ss[tid] | ss[tid + 64];
  int any = __any(lrst != 0);
  if (tid == 0 && tg == 0) rstflag[c * B_DIM + bb] = any;

  float decay = expf(-fabsf(ffm_a[trace]));
  float th = ffm_b[cx];
  float cr = decay * cosf(th);
  float ci = decay * sinf(th);
  float sr = 0.f, si = 0.f;
  for (int t = 0; t < CHL; ++t) {
    float g = gs[t * 4 + tl];
    int rst = ss[t];
    float nr = fmaf(sr, cr, fmaf(-si, ci, g));
    float ni = fmaf(sr, ci, si * cr);
    sr = rst ? g : nr;
    si = rst ? 0.f : ni;
  }
  carry[((size_t)(c * B_DIM + bb) * TRACE + trace) * CTX + cx] =
      make_float2(sr, si);
}

// ---------------------------------------------------------------------------
// K2c: combine carries -> chunk-start state, then scan chunk writing zin
// (packed re|im<<16 uint per (trace,cx)). chunk 7 writes fstate (real).
// ---------------------------------------------------------------------------
__global__ __launch_bounds__(64) void k_scan_c(
    const __hip_bfloat16* __restrict__ proj, const int* __restrict__ startw,
    const float* __restrict__ state_re, const float* __restrict__ state_im,
    const float* __restrict__ ffm_a, const float* __restrict__ ffm_b,
    const float2* __restrict__ carry, const int* __restrict__ rstflag,
    __hip_bfloat16* __restrict__ zin, float* __restrict__ fstate) {
  const int c  = blockIdx.x >> 9;        // 0..7
  const int bb = (blockIdx.x >> 4) & 31;
  const int tg = blockIdx.x & 15;
  const int tid = threadIdx.x;
  const int tl = tid >> 4, cx = tid & 15;
  const int trace = tg * 4 + tl;
  const int t0 = c * CHL;
  __shared__ float gs[CHL * 4];
  __shared__ int ss[CHL];
  for (int t = tid; t < CHL; t += 64) {
    size_t base = ((size_t)(t0 + t) * B_DIM + bb) * NP + tg * 4;
    ushortx4 pg4 = *reinterpret_cast<const ushortx4*>(proj + base);
    ushortx4 pp4 = *reinterpret_cast<const ushortx4*>(proj + base + 64);
    float4 o;
    o.x = bf2f(pp4[0]) * sigm(bf2f(pg4[0]));
    o.y = bf2f(pp4[1]) * sigm(bf2f(pg4[1]));
    o.z = bf2f(pp4[2]) * sigm(bf2f(pg4[2]));
    o.w = bf2f(pp4[3]) * sigm(bf2f(pg4[3]));
    *reinterpret_cast<float4*>(&gs[t * 4]) = o;
    ss[t] = startw[(t0 + t) * B_DIM + bb];
  }
  __syncthreads();

  float decay = expf(-fabsf(ffm_a[trace]));
  float th = ffm_b[cx];
  float cr = decay * cosf(th);
  float ci = decay * sinf(th);

  float pr = cr, pi = ci;
#pragma unroll
  for (int q = 0; q < 7; ++q) {
    float nr = pr * pr - pi * pi;
    float ni = 2.f * pr * pi;
    pr = nr; pi = ni;
  }

  const int chain = (bb * TRACE + trace) * CTX + cx;
  float sr = state_re[chain];
  float si = state_im[chain];
  for (int j = 0; j < c; ++j) {
    float2 cj = carry[((size_t)(j * B_DIM + bb) * TRACE + trace) * CTX + cx];
    if (rstflag[j * B_DIM + bb]) {
      sr = cj.x; si = cj.y;
    } else {
      float nsr = fmaf(pr, sr, fmaf(-pi, si, cj.x));
      float nsi = fmaf(pr, si, fmaf(pi, sr, cj.y));
      sr = nsr; si = nsi;
    }
  }

  const size_t zbase = (size_t)trace * 32 + cx * 2;
  for (int t = 0; t < CHL; ++t) {
    float g = gs[t * 4 + tl];
    int rst = ss[t];
    float nr = fmaf(sr, cr, fmaf(-si, ci, g));
    float ni = fmaf(sr, ci, si * cr);
    sr = rst ? g : nr;
    si = rst ? 0.f : ni;
    unsigned int u = (unsigned int)__bfloat16_as_ushort(__float2bfloat16(sr)) |
                     ((unsigned int)__bfloat16_as_ushort(__float2bfloat16(si)) << 16);
    *reinterpret_cast<unsigned int*>(
        zin + ((size_t)(t0 + t) * B_DIM + bb) * KZ + zbase) = u;
  }
  if (c == NCH - 1) fstate[chain] = sr;
}

extern "C" void kernel_launch(void* const* d_in, const int* in_sizes, int n_in,
                              void* d_out, int out_size, void* d_ws, size_t ws_size,
                              hipStream_t stream) {
  const float* x         = (const float*)d_in[0];
  const unsigned char* start_raw = (const unsigned char*)d_in[1];
  const float* state_re  = (const float*)d_in[2];
  const float* state_im  = (const float*)d_in[3];
  const float* w_gate_in = (const float*)d_in[4];
  const float* b_gate_in = (const float*)d_in[5];
  const float* w_pre     = (const float*)d_in[6];
  const float* b_pre     = (const float*)d_in[7];
  const float* w_z       = (const float*)d_in[8];
  const float* b_z       = (const float*)d_in[9];
  const float* w_gate_out= (const float*)d_in[10];
  const float* b_gate_out= (const float*)d_in[11];
  const float* w_skip    = (const float*)d_in[12];
  const float* b_skip    = (const float*)d_in[13];
  const float* ffm_a     = (const float*)d_in[14];
  const float* ffm_b     = (const float*)d_in[15];

  // workspace layout
  char* ws = (char*)d_ws;
  int* flag     = (int*)ws;                                   // [0, 4KB)
  int* startw   = (int*)(ws + 4096);                          // [4KB, 132KB)
  int* rstflag  = (int*)(ws + (132 << 10));                   // [132KB, 133KB)
  float* bcat   = (float*)(ws + (160 << 10));                 // [160KB, 163KB)
  __hip_bfloat16* wcat =
      (__hip_bfloat16*)(ws + (256 << 10));                    // [256KB, 576KB)
  __hip_bfloat16* wzt =
      (__hip_bfloat16*)(ws + ((size_t)1 << 20));              // [1MB, 2MB)
  float2* carry = (float2*)(ws + ((size_t)2 << 20));          // [2MB, 4MB)
  __hip_bfloat16* proj =
      (__hip_bfloat16*)(ws + ((size_t)4 << 20));              // [4MB, 44MB)
  __hip_bfloat16* zin =
      (__hip_bfloat16*)(ws + ((size_t)60 << 20));             // [60MB, 188MB)

  float* fstate = (float*)d_out;                    // real(final_state), 32768
  float* out    = (float*)d_out + B_DIM * TRACE * CTX;

  k_start_detect<<<1, 256, 0, stream>>>(start_raw, flag);
  k_start_unpack<<<TB / 256, 256, 0, stream>>>(start_raw, flag, startw);
  k_prep_cat<<<NP, 256, 0, stream>>>(w_gate_in, b_gate_in, w_pre, b_pre,
                                     w_gate_out, b_gate_out, w_skip, b_skip,
                                     wcat, bcat);
  k_gemm_xproj<<<dim3(NP / 128, TB / 128), 256, 0, stream>>>(
      x, wcat, bcat, proj);
  k_prep<<<128, 256, 0, stream>>>(w_z, wzt);
  k_scan_a<<<(NCH - 1) * B_DIM * 16, 64, 0, stream>>>(
      proj, startw, ffm_a, ffm_b, carry, rstflag);
  k_scan_c<<<NCH * B_DIM * 16, 64, 0, stream>>>(
      proj, startw, state_re, state_im, ffm_a, ffm_b, carry, rstflag,
      zin, fstate);
  k_zgemm_ln<<<TB / 64, 256, 0, stream>>>(zin, wzt, b_z, proj, out);
}

// Round 11
// 184.668 us; speedup vs baseline: 6.5503x; 1.0357x over previous
//
#include <hip/hip_runtime.h>
#include <hip/hip_bf16.h>

#define T_DIM 1024
#define B_DIM 32
#define D_DIM 256
#define TRACE 64
#define CTX 16
#define OUT_DIM 256
#define TB (T_DIM * B_DIM)          // 32768 rows
#define KZ (2 * TRACE * CTX)        // 2048
#define NP 640                      // concat proj width
#define NCH 8                       // scan chunks
#define CHL 128                     // chunk length

typedef short short8 __attribute__((ext_vector_type(8)));
typedef float floatx4 __attribute__((ext_vector_type(4)));
typedef unsigned short ushortx4 __attribute__((ext_vector_type(4)));

__device__ __forceinline__ float bf2f(unsigned short u) {
  return __uint_as_float((unsigned int)u << 16);
}
__device__ __forceinline__ float sigm(float v) {
  return 1.f / (1.f + expf(-v));
}
// async global->LDS, 16B per lane; LDS dest = uniform base + lane*16
__device__ __forceinline__ void gload_lds16(const void* g, void* l) {
  __builtin_amdgcn_global_load_lds(
      (const __attribute__((address_space(1))) void*)g,
      (__attribute__((address_space(3))) void*)l, 16, 0, 0);
}

// ---------------------------------------------------------------------------
// K0a: unpack `start` to int32; encoding flag derived per-block (merged
// detect+unpack; deterministic).
//   bool(1B): nonzero at i%4==1 -> 1 ; f32: i%4==3 -> 2 ;
//   int32: i%8==4 -> 0 ; else int64 -> 3
// ---------------------------------------------------------------------------
__global__ __launch_bounds__(256) void k_start_unpack(
    const unsigned char* __restrict__ s, int* __restrict__ out) {
  __shared__ int a1, a3, a4;
  if (threadIdx.x == 0) { a1 = 0; a3 = 0; a4 = 0; }
  __syncthreads();
  int l1 = 0, l3 = 0, l4 = 0;
  for (int i = threadIdx.x; i < 32768; i += 256) {
    unsigned char v = s[i];
    if (v) {
      if ((i & 3) == 1) l1 = 1;
      if ((i & 3) == 3) l3 = 1;
      if ((i & 7) == 4) l4 = 1;
    }
  }
  if (l1) atomicOr(&a1, 1);
  if (l3) atomicOr(&a3, 1);
  if (l4) atomicOr(&a4, 1);
  __syncthreads();
  int f = a1 ? 1 : (a3 ? 2 : (a4 ? 0 : 3));
  int i = blockIdx.x * 256 + threadIdx.x;   // 32768 total (128 blocks)
  int v;
  if (f == 1)      v = s[i] != 0;
  else if (f == 2) v = reinterpret_cast<const float*>(s)[i] != 0.f;
  else if (f == 3) v = reinterpret_cast<const long long*>(s)[i] != 0;
  else             v = reinterpret_cast<const int*>(s)[i] != 0;
  out[i] = v;
}

// ---------------------------------------------------------------------------
// K0b: wzt[n][k'] = bf16(w_z[perm(k')][n]); zin K is permuted so (re,im) of a
// ctx are adjacent: k' = trace*32 + cx*2 + ri ; source k = trace*32 + ri*16 + cx
// ---------------------------------------------------------------------------
__global__ __launch_bounds__(256) void k_prep(
    const float* __restrict__ wz, __hip_bfloat16* __restrict__ wzt) {
  const int tk = blockIdx.x & 31;
  const int tn = blockIdx.x >> 5;
  const int k0 = tk * 64, n0 = tn * 64;
  __shared__ float sm[64][65];
  const int tid = threadIdx.x;
  for (int i = tid; i < 4096; i += 256) {
    int r = i >> 6, c = i & 63;
    sm[r][c] = wz[(size_t)(k0 + r) * 256 + n0 + c];
  }
  __syncthreads();
  for (int i = tid; i < 4096; i += 256) {
    int r = i >> 6, c = i & 63;   // r: n-within, c: k'-within (output)
    int src = (c & 0x20) | ((c & 1) << 4) | ((c >> 1) & 15);
    wzt[(size_t)(n0 + r) * 2048 + k0 + c] = __float2bfloat16(sm[src][r]);
  }
}

// ---------------------------------------------------------------------------
// K0c: wcat[n][k] = bf16 of transposed concat [w_gate_in|w_pre|w_gate_out|w_skip]
// ---------------------------------------------------------------------------
__global__ __launch_bounds__(256) void k_prep_cat(
    const float* __restrict__ wgi, const float* __restrict__ bgi,
    const float* __restrict__ wpr, const float* __restrict__ bpr,
    const float* __restrict__ wgo, const float* __restrict__ bgo,
    const float* __restrict__ wsk, const float* __restrict__ bsk,
    __hip_bfloat16* __restrict__ wcat, float* __restrict__ bcat) {
  const int n = blockIdx.x, k = threadIdx.x;
  float v, bv;
  if (n < 64)        { v = wgi[k * 64 + n];          bv = bgi[n]; }
  else if (n < 128)  { v = wpr[k * 64 + (n - 64)];   bv = bpr[n - 64]; }
  else if (n < 384)  { v = wgo[k * 256 + (n - 128)]; bv = bgo[n - 128]; }
  else               { v = wsk[k * 256 + (n - 384)]; bv = bsk[n - 384]; }
  wcat[(size_t)n * 256 + k] = __float2bfloat16(v);
  if (k == 0) bcat[n] = bv;
}

// ---------------------------------------------------------------------------
// Proj GEMM: proj = bf16( f32(x) @ wcat^T + bcat ). M=32768, K=256, N=640.
// A reg-staged (f32->bf16 cast); B via global_load_lds w/ pre-swizzled source.
// ---------------------------------------------------------------------------
__global__ __launch_bounds__(256) void k_gemm_xproj(
    const float* __restrict__ A, const __hip_bfloat16* __restrict__ Bm,
    const float* __restrict__ bias, __hip_bfloat16* __restrict__ C) {
  const int r0 = blockIdx.y * 128;
  const int n0 = blockIdx.x * 128;
  const int tid = threadIdx.x;
  const int l = tid & 63;
  const int wid = tid >> 6;
  const int wr = wid >> 1;
  const int wc = wid & 1;

  __shared__ __align__(16) char ldsA[16384];
  __shared__ __align__(16) char ldsB[16384];

  floatx4 acc[4][4];
#pragma unroll
  for (int m = 0; m < 4; ++m)
#pragma unroll
    for (int n = 0; n < 4; ++n) acc[m][n] = (floatx4)0.f;

  int aoff[4][2], boff[4][2];
#pragma unroll
  for (int m = 0; m < 4; ++m) {
    int row = wr * 64 + m * 16 + (l & 15);
#pragma unroll
    for (int ks = 0; ks < 2; ++ks) {
      int byte = row * 128 + ks * 64 + (l >> 4) * 16;
      aoff[m][ks] = byte ^ ((row & 7) << 4);
    }
    int col = wc * 64 + m * 16 + (l & 15);
#pragma unroll
    for (int ks = 0; ks < 2; ++ks) {
      int byte = col * 128 + ks * 64 + (l >> 4) * 16;
      boff[m][ks] = byte ^ ((col & 7) << 4);
    }
  }

  for (int kt = 0; kt < 256; kt += 64) {
    // B: 128 rows x 8 chunks, linear LDS + pre-swizzled global source
#pragma unroll
    for (int i = 0; i < 4; ++i) {
      int c = tid + i * 256;
      int row = c >> 3;
      int kgs = (c & 7) ^ (row & 7);
      gload_lds16(Bm + (size_t)(n0 + row) * 256 + kt + kgs * 8,
                  ldsB + i * 4096 + wid * 1024);
    }
    // A: reg-staged with f32->bf16 cast, swizzled ds_write
#pragma unroll
    for (int i = 0; i < 4; ++i) {
      int c = tid + i * 256;
      int row = c >> 3, kg = c & 7;
      int byte = (row * 128 + kg * 16) ^ ((row & 7) << 4);
      const float* ap = A + (size_t)(r0 + row) * 256 + kt + kg * 8;
      float4 a0 = *reinterpret_cast<const float4*>(ap);
      float4 a1 = *reinterpret_cast<const float4*>(ap + 4);
      unsigned short u[8];
      u[0] = __bfloat16_as_ushort(__float2bfloat16(a0.x));
      u[1] = __bfloat16_as_ushort(__float2bfloat16(a0.y));
      u[2] = __bfloat16_as_ushort(__float2bfloat16(a0.z));
      u[3] = __bfloat16_as_ushort(__float2bfloat16(a0.w));
      u[4] = __bfloat16_as_ushort(__float2bfloat16(a1.x));
      u[5] = __bfloat16_as_ushort(__float2bfloat16(a1.y));
      u[6] = __bfloat16_as_ushort(__float2bfloat16(a1.z));
      u[7] = __bfloat16_as_ushort(__float2bfloat16(a1.w));
      *reinterpret_cast<uint4*>(ldsA + byte) = *reinterpret_cast<uint4*>(u);
    }
    __syncthreads();
#pragma unroll
    for (int ks = 0; ks < 2; ++ks) {
      short8 a[4], b[4];
#pragma unroll
      for (int m = 0; m < 4; ++m)
        a[m] = *reinterpret_cast<const short8*>(ldsA + aoff[m][ks]);
#pragma unroll
      for (int n = 0; n < 4; ++n)
        b[n] = *reinterpret_cast<const short8*>(ldsB + boff[n][ks]);
#pragma unroll
      for (int m = 0; m < 4; ++m)
#pragma unroll
        for (int n = 0; n < 4; ++n)
          acc[m][n] = __builtin_amdgcn_mfma_f32_16x16x32_bf16(
              a[m], b[n], acc[m][n], 0, 0, 0);
    }
    __syncthreads();
  }

#pragma unroll
  for (int m = 0; m < 4; ++m) {
#pragma unroll
    for (int n = 0; n < 4; ++n) {
      int gc = n0 + wc * 64 + n * 16 + (l & 15);
      float bzv = bias[gc];
#pragma unroll
      for (int j = 0; j < 4; ++j) {
        int gr = r0 + wr * 64 + m * 16 + (l >> 4) * 4 + j;
        C[(size_t)gr * NP + gc] = __float2bfloat16(acc[m][n][j] + bzv);
      }
    }
  }
}

// ---------------------------------------------------------------------------
// Fused z-GEMM + LayerNorm epilogue, v3: global_load_lds staging.
// Tile 64M x 256N, grid 512 blocks. 4 waves split N (4m x 4n frags each).
// LDS linear, global source pre-swizzled (kg ^= row&7) so XOR'd reads match.
// ---------------------------------------------------------------------------
__global__ __launch_bounds__(256, 2) void k_zgemm_ln(
    const __hip_bfloat16* __restrict__ zin, const __hip_bfloat16* __restrict__ wzt,
    const float* __restrict__ bz, const __hip_bfloat16* __restrict__ proj,
    float* __restrict__ out) {
  const int r0 = blockIdx.x * 64;
  const int tid = threadIdx.x;
  const int l = tid & 63;
  const int w = tid >> 6;            // wave id = N-slice

  __shared__ __align__(16) char ldsA[8192];    // [64][64] bf16 (swz content)
  __shared__ __align__(16) char ldsB[32768];   // [256][64] bf16 (swz content)
  __shared__ float red1[64][4], red2[64][4];

  floatx4 acc[4][4];
#pragma unroll
  for (int m = 0; m < 4; ++m)
#pragma unroll
    for (int n = 0; n < 4; ++n) acc[m][n] = (floatx4)0.f;

  int aoff[4][2], boff[4][2];
#pragma unroll
  for (int m = 0; m < 4; ++m) {
    int row = m * 16 + (l & 15);
#pragma unroll
    for (int ks = 0; ks < 2; ++ks) {
      int byte = row * 128 + ks * 64 + (l >> 4) * 16;
      aoff[m][ks] = byte ^ ((row & 7) << 4);
    }
  }
#pragma unroll
  for (int n = 0; n < 4; ++n) {
    int col = w * 64 + n * 16 + (l & 15);
#pragma unroll
    for (int ks = 0; ks < 2; ++ks) {
      int byte = col * 128 + ks * 64 + (l >> 4) * 16;
      boff[n][ks] = byte ^ ((col & 7) << 4);
    }
  }

  for (int kt = 0; kt < KZ; kt += 64) {
    // A: 64 rows x 8 chunks = 512 (2 gload_lds per thread)
#pragma unroll
    for (int i = 0; i < 2; ++i) {
      int c = tid + i * 256;
      int row = c >> 3;
      int kgs = (c & 7) ^ (row & 7);
      gload_lds16(zin + (size_t)(r0 + row) * KZ + kt + kgs * 8,
                  ldsA + i * 4096 + w * 1024);
    }
    // B: 256 rows x 8 chunks = 2048 (8 gload_lds per thread)
#pragma unroll
    for (int i = 0; i < 8; ++i) {
      int c = tid + i * 256;
      int row = c >> 3;
      int kgs = (c & 7) ^ (row & 7);
      gload_lds16(wzt + (size_t)row * KZ + kt + kgs * 8,
                  ldsB + i * 4096 + w * 1024);
    }
    __syncthreads();
#pragma unroll
    for (int ks = 0; ks < 2; ++ks) {
      short8 a[4], b[4];
#pragma unroll
      for (int m = 0; m < 4; ++m)
        a[m] = *reinterpret_cast<const short8*>(ldsA + aoff[m][ks]);
#pragma unroll
      for (int n = 0; n < 4; ++n)
        b[n] = *reinterpret_cast<const short8*>(ldsB + boff[n][ks]);
#pragma unroll
      for (int m = 0; m < 4; ++m)
#pragma unroll
        for (int n = 0; n < 4; ++n)
          acc[m][n] = __builtin_amdgcn_mfma_f32_16x16x32_bf16(
              a[m], b[n], acc[m][n], 0, 0, 0);
    }
    __syncthreads();
  }

  float bzv[4];
#pragma unroll
  for (int n = 0; n < 4; ++n) bzv[n] = bz[w * 64 + n * 16 + (l & 15)];

  // phase 1: y in-place into acc, q = ps*(1-go), wave-local partial sums
  float q[4][4][4];
#pragma unroll
  for (int m = 0; m < 4; ++m) {
#pragma unroll
    for (int j = 0; j < 4; ++j) {
      int row = m * 16 + (l >> 4) * 4 + j;
      const __hip_bfloat16* prow = proj + (size_t)(r0 + row) * NP;
      float s1 = 0.f, s2 = 0.f;
#pragma unroll
      for (int n = 0; n < 4; ++n) {
        int col = w * 64 + n * 16 + (l & 15);
        float go = sigm(__bfloat162float(prow[128 + col]));
        float ps = __bfloat162float(prow[384 + col]);
        float y = (acc[m][n][j] + bzv[n]) * go;
        acc[m][n][j] = y;
        q[m][n][j] = ps * (1.f - go);
        s1 += y;
        s2 += y * y;
      }
#pragma unroll
      for (int off = 8; off > 0; off >>= 1) {
        s1 += __shfl_xor(s1, off);
        s2 += __shfl_xor(s2, off);
      }
      if ((l & 15) == 0) { red1[row][w] = s1; red2[row][w] = s2; }
    }
  }
  __syncthreads();

  // phase 2: combine cross-wave sums, normalize, write out
#pragma unroll
  for (int m = 0; m < 4; ++m) {
#pragma unroll
    for (int j = 0; j < 4; ++j) {
      int row = m * 16 + (l >> 4) * 4 + j;
      int gr = r0 + row;
      float t1 = red1[row][0] + red1[row][1] + red1[row][2] + red1[row][3];
      float t2 = red2[row][0] + red2[row][1] + red2[row][2] + red2[row][3];
      float mu = t1 * (1.f / 256.f);
      float var = t2 * (1.f / 256.f) - mu * mu;
      float rs = rsqrtf(var + 1e-6f);
#pragma unroll
      for (int n = 0; n < 4; ++n) {
        int col = w * 64 + n * 16 + (l & 15);
        out[(size_t)gr * 256 + col] = (acc[m][n][j] - mu) * rs + q[m][n][j];
      }
    }
  }
}

// ---------------------------------------------------------------------------
// K2a: per-chunk local scan -> carry s_c (complex) per chain; rst_any per
// (chunk,b). block = (chunk<7, b, tg); 64 threads = (tl 0..3, cx 0..15).
// ---------------------------------------------------------------------------
__global__ __launch_bounds__(64) void k_scan_a(
    const __hip_bfloat16* __restrict__ proj, const int* __restrict__ startw,
    const float* __restrict__ ffm_a, const float* __restrict__ ffm_b,
    float2* __restrict__ carry, int* __restrict__ rstflag) {
  const int c  = blockIdx.x >> 9;        // 0..6
  const int bb = (blockIdx.x >> 4) & 31;
  const int tg = blockIdx.x & 15;
  const int tid = threadIdx.x;
  const int tl = tid >> 4, cx = tid & 15;
  const int trace = tg * 4 + tl;
  const int t0 = c * CHL;
  __shared__ float gs[CHL * 4];
  __shared__ int ss[CHL];
  for (int t = tid; t < CHL; t += 64) {
    size_t base = ((size_t)(t0 + t) * B_DIM + bb) * NP + tg * 4;
    ushortx4 pg4 = *reinterpret_cast<const ushortx4*>(proj + base);
    ushortx4 pp4 = *reinterpret_cast<const ushortx4*>(proj + base + 64);
    float4 o;
    o.x = bf2f(pp4[0]) * sigm(bf2f(pg4[0]));
    o.y = bf2f(pp4[1]) * sigm(bf2f(pg4[1]));
    o.z = bf2f(pp4[2]) * sigm(bf2f(pg4[2]));
    o.w = bf2f(pp4[3]) * sigm(bf2f(pg4[3]));
    *reinterpret_cast<float4*>(&gs[t * 4]) = o;
    ss[t] = startw[(t0 + t) * B_DIM + bb];
  }
  __syncthreads();

  int lrst = ss[tid] | ss[tid + 64];
  int any = __any(lrst != 0);
  if (tid == 0 && tg == 0) rstflag[c * B_DIM + bb] = any;

  float decay = expf(-fabsf(ffm_a[trace]));
  float th = ffm_b[cx];
  float cr = decay * cosf(th);
  float ci = decay * sinf(th);
  float sr = 0.f, si = 0.f;
  for (int t = 0; t < CHL; ++t) {
    float g = gs[t * 4 + tl];
    int rst = ss[t];
    float nr = fmaf(sr, cr, fmaf(-si, ci, g));
    float ni = fmaf(sr, ci, si * cr);
    sr = rst ? g : nr;
    si = rst ? 0.f : ni;
  }
  carry[((size_t)(c * B_DIM + bb) * TRACE + trace) * CTX + cx] =
      make_float2(sr, si);
}

// ---------------------------------------------------------------------------
// K2c: combine carries -> chunk-start state, then scan chunk writing zin
// (packed re|im<<16 uint per (trace,cx)). chunk 7 writes fstate (real).
// ---------------------------------------------------------------------------
__global__ __launch_bounds__(64) void k_scan_c(
    const __hip_bfloat16* __restrict__ proj, const int* __restrict__ startw,
    const float* __restrict__ state_re, const float* __restrict__ state_im,
    const float* __restrict__ ffm_a, const float* __restrict__ ffm_b,
    const float2* __restrict__ carry, const int* __restrict__ rstflag,
    __hip_bfloat16* __restrict__ zin, float* __restrict__ fstate) {
  const int c  = blockIdx.x >> 9;        // 0..7
  const int bb = (blockIdx.x >> 4) & 31;
  const int tg = blockIdx.x & 15;
  const int tid = threadIdx.x;
  const int tl = tid >> 4, cx = tid & 15;
  const int trace = tg * 4 + tl;
  const int t0 = c * CHL;
  __shared__ float gs[CHL * 4];
  __shared__ int ss[CHL];
  for (int t = tid; t < CHL; t += 64) {
    size_t base = ((size_t)(t0 + t) * B_DIM + bb) * NP + tg * 4;
    ushortx4 pg4 = *reinterpret_cast<const ushortx4*>(proj + base);
    ushortx4 pp4 = *reinterpret_cast<const ushortx4*>(proj + base + 64);
    float4 o;
    o.x = bf2f(pp4[0]) * sigm(bf2f(pg4[0]));
    o.y = bf2f(pp4[1]) * sigm(bf2f(pg4[1]));
    o.z = bf2f(pp4[2]) * sigm(bf2f(pg4[2]));
    o.w = bf2f(pp4[3]) * sigm(bf2f(pg4[3]));
    *reinterpret_cast<float4*>(&gs[t * 4]) = o;
    ss[t] = startw[(t0 + t) * B_DIM + bb];
  }
  __syncthreads();

  float decay = expf(-fabsf(ffm_a[trace]));
  float th = ffm_b[cx];
  float cr = decay * cosf(th);
  float ci = decay * sinf(th);

  float pr = cr, pi = ci;
#pragma unroll
  for (int q = 0; q < 7; ++q) {
    float nr = pr * pr - pi * pi;
    float ni = 2.f * pr * pi;
    pr = nr; pi = ni;
  }

  const int chain = (bb * TRACE + trace) * CTX + cx;
  float sr = state_re[chain];
  float si = state_im[chain];
  for (int j = 0; j < c; ++j) {
    float2 cj = carry[((size_t)(j * B_DIM + bb) * TRACE + trace) * CTX + cx];
    if (rstflag[j * B_DIM + bb]) {
      sr = cj.x; si = cj.y;
    } else {
      float nsr = fmaf(pr, sr, fmaf(-pi, si, cj.x));
      float nsi = fmaf(pr, si, fmaf(pi, sr, cj.y));
      sr = nsr; si = nsi;
    }
  }

  const size_t zbase = (size_t)trace * 32 + cx * 2;
  for (int t = 0; t < CHL; ++t) {
    float g = gs[t * 4 + tl];
    int rst = ss[t];
    float nr = fmaf(sr, cr, fmaf(-si, ci, g));
    float ni = fmaf(sr, ci, si * cr);
    sr = rst ? g : nr;
    si = rst ? 0.f : ni;
    unsigned int u = (unsigned int)__bfloat16_as_ushort(__float2bfloat16(sr)) |
                     ((unsigned int)__bfloat16_as_ushort(__float2bfloat16(si)) << 16);
    *reinterpret_cast<unsigned int*>(
        zin + ((size_t)(t0 + t) * B_DIM + bb) * KZ + zbase) = u;
  }
  if (c == NCH - 1) fstate[chain] = sr;
}

extern "C" void kernel_launch(void* const* d_in, const int* in_sizes, int n_in,
                              void* d_out, int out_size, void* d_ws, size_t ws_size,
                              hipStream_t stream) {
  const float* x         = (const float*)d_in[0];
  const unsigned char* start_raw = (const unsigned char*)d_in[1];
  const float* state_re  = (const float*)d_in[2];
  const float* state_im  = (const float*)d_in[3];
  const float* w_gate_in = (const float*)d_in[4];
  const float* b_gate_in = (const float*)d_in[5];
  const float* w_pre     = (const float*)d_in[6];
  const float* b_pre     = (const float*)d_in[7];
  const float* w_z       = (const float*)d_in[8];
  const float* b_z       = (const float*)d_in[9];
  const float* w_gate_out= (const float*)d_in[10];
  const float* b_gate_out= (const float*)d_in[11];
  const float* w_skip    = (const float*)d_in[12];
  const float* b_skip    = (const float*)d_in[13];
  const float* ffm_a     = (const float*)d_in[14];
  const float* ffm_b     = (const float*)d_in[15];

  // workspace layout
  char* ws = (char*)d_ws;
  int* startw   = (int*)(ws + 4096);                          // [4KB, 132KB)
  int* rstflag  = (int*)(ws + (132 << 10));                   // [132KB, 133KB)
  float* bcat   = (float*)(ws + (160 << 10));                 // [160KB, 163KB)
  __hip_bfloat16* wcat =
      (__hip_bfloat16*)(ws + (256 << 10));                    // [256KB, 576KB)
  __hip_bfloat16* wzt =
      (__hip_bfloat16*)(ws + ((size_t)1 << 20));              // [1MB, 2MB)
  float2* carry = (float2*)(ws + ((size_t)2 << 20));          // [2MB, 4MB)
  __hip_bfloat16* proj =
      (__hip_bfloat16*)(ws + ((size_t)4 << 20));              // [4MB, 44MB)
  __hip_bfloat16* zin =
      (__hip_bfloat16*)(ws + ((size_t)60 << 20));             // [60MB, 188MB)

  float* fstate = (float*)d_out;                    // real(final_state), 32768
  float* out    = (float*)d_out + B_DIM * TRACE * CTX;

  k_start_unpack<<<TB / 256, 256, 0, stream>>>(start_raw, startw);
  k_prep_cat<<<NP, 256, 0, stream>>>(w_gate_in, b_gate_in, w_pre, b_pre,
                                     w_gate_out, b_gate_out, w_skip, b_skip,
                                     wcat, bcat);
  k_gemm_xproj<<<dim3(NP / 128, TB / 128), 256, 0, stream>>>(
      x, wcat, bcat, proj);
  k_prep<<<128, 256, 0, stream>>>(w_z, wzt);
  k_scan_a<<<(NCH - 1) * B_DIM * 16, 64, 0, stream>>>(
      proj, startw, ffm_a, ffm_b, carry, rstflag);
  k_scan_c<<<NCH * B_DIM * 16, 64, 0, stream>>>(
      proj, startw, state_re, state_im, ffm_a, ffm_b, carry, rstflag,
      zin, fstate);
  k_zgemm_ln<<<TB / 64, 256, 0, stream>>>(zin, wzt, b_z, proj, out);
}